// Round 8
// baseline (342.923 us; speedup 1.0000x reference)
//
#include <hip/hip_runtime.h>
#include <hip/hip_bf16.h>
#include <stdint.h>

#define S 128
#define R 256
#define CM 256
#define CZ 128
#define H 8
#define D 32

typedef __attribute__((ext_vector_type(8))) short short8;
typedef __attribute__((ext_vector_type(4))) float f32x4;
typedef __attribute__((ext_vector_type(16))) float f32x16;
typedef __attribute__((ext_vector_type(2))) unsigned uint2v;
typedef unsigned short u16;

#define LOG2E 1.4426950408889634f

// ---------- helpers ----------
__device__ __forceinline__ float wsum(float v) {
#pragma unroll
  for (int o = 32; o > 0; o >>= 1) v += __shfl_xor(v, o, 64);
  return v;
}
__device__ __forceinline__ u16 f2bb(float f) {
  unsigned u = __float_as_uint(f);
  return (u16)((u + 0x7fffu + ((u >> 16) & 1u)) >> 16);
}
__device__ __forceinline__ float b2f(u16 u) {
  return __uint_as_float(((unsigned)u) << 16);
}
__device__ __forceinline__ unsigned pkbf16(float a, float b) {
  __hip_bfloat162 t = __float22bfloat162_rn(make_float2(a, b));
  union { __hip_bfloat162 h; unsigned u; } cv;
  cv.h = t;
  return cv.u;
}
__device__ __forceinline__ void gl_lds16(const u16* g, u16* l) {
  __builtin_amdgcn_global_load_lds(
      (const __attribute__((address_space(1))) unsigned int*)g,
      (__attribute__((address_space(3))) unsigned int*)l, 16, 0, 0);
}

// stage a [128 rows][64 cols] bf16 tile (src row stride 256 elems) into linear LDS.
__device__ __forceinline__ void stage_tile(const u16* __restrict__ src, u16* lbase,
                                           int w, int l) {
#pragma unroll
  for (int it = 0; it < 4; it++) {
    int rbase = it * 32 + w * 8;
    int row = rbase + (l >> 3);
    int gc8 = (l & 7) ^ (row & 7);
    gl_lds16(src + (size_t)row * 256 + gc8 * 8, lbase + rbase * 64);
  }
}

// ---------- kernel 0: weights -> bf16, transposed [hd'][c]; qscale*log2e folded ----------
__global__ __launch_bounds__(256) void k_prep(const float* __restrict__ wq,
                                              const float* __restrict__ wk,
                                              const float* __restrict__ wv,
                                              const float* __restrict__ wg,
                                              const float* __restrict__ wo,
                                              u16* __restrict__ wcat_t,
                                              u16* __restrict__ wot) {
  __shared__ float t[64][65];
  int mat = blockIdx.y;  // 0..4
  const float* src = (mat == 0) ? wq : (mat == 1) ? wk : (mat == 2) ? wv
                     : (mat == 3) ? wg : wo;
  // q: 1/sqrt(D) * log2(e) folded (softmax uses exp2)
  float scale = (mat == 0) ? 0.17677669529663687f * LOG2E : 1.0f;
  u16* dst = (mat < 4) ? (wcat_t + mat * 256 * 256) : wot;
  int ti = blockIdx.x >> 2, tj = blockIdx.x & 3;
  int tid = threadIdx.x;
  int cc = tid & 63, rr4 = tid >> 6;
#pragma unroll
  for (int it = 0; it < 16; it++) {
    int ic = it * 4 + rr4;
    t[ic][cc] = src[(tj * 64 + ic) * 256 + ti * 64 + cc];
  }
  __syncthreads();
#pragma unroll
  for (int it = 0; it < 16; it++) {
    int oh = it * 4 + rr4;
    dst[(ti * 64 + oh) * 256 + tj * 64 + cc] = f2bb(t[cc][oh] * scale);
  }
}

// ---------- kernel 1: pair bias -> bf16  zbb[h][q*256+col], log2e folded ----------
__global__ __launch_bounds__(256) void k_zbias(const float* __restrict__ z,
                                               const float* __restrict__ lng,
                                               const float* __restrict__ lnb,
                                               const float* __restrict__ wz,
                                               u16* __restrict__ zbb) {
  int tid = threadIdx.x;
  int l = tid & 63, w = tid >> 6;
  int psub = l >> 3, cg = l & 7;
  int op = blockIdx.x * 32 + w * 8 + psub;   // op = q*256 + col
  const float* zr = z + (size_t)op * CZ;
  float4 v[4];
#pragma unroll
  for (int i = 0; i < 4; i++) v[i] = *(const float4*)(zr + i * 32 + cg * 4);
  float sum = 0.f, ssq = 0.f;
#pragma unroll
  for (int i = 0; i < 4; i++) {
    sum += v[i].x + v[i].y + v[i].z + v[i].w;
    ssq += v[i].x * v[i].x + v[i].y * v[i].y + v[i].z * v[i].z + v[i].w * v[i].w;
  }
  sum += __shfl_xor(sum, 1, 64); sum += __shfl_xor(sum, 2, 64); sum += __shfl_xor(sum, 4, 64);
  ssq += __shfl_xor(ssq, 1, 64); ssq += __shfl_xor(ssq, 2, 64); ssq += __shfl_xor(ssq, 4, 64);
  float mu = sum * (1.0f / CZ);
  float rs = rsqrtf(ssq * (1.0f / CZ) - mu * mu + 1e-5f);
  float ph[8];
#pragma unroll
  for (int hh = 0; hh < 8; hh++) ph[hh] = 0.f;
#pragma unroll
  for (int i = 0; i < 4; i++) {
    int c0 = i * 32 + cg * 4;
    float4 gg = *(const float4*)(lng + c0);
    float4 bb = *(const float4*)(lnb + c0);
    float n0 = (v[i].x - mu) * rs * gg.x + bb.x;
    float n1 = (v[i].y - mu) * rs * gg.y + bb.y;
    float n2 = (v[i].z - mu) * rs * gg.z + bb.z;
    float n3 = (v[i].w - mu) * rs * gg.w + bb.w;
#pragma unroll
    for (int jj = 0; jj < 4; jj++) {
      float nj = (jj == 0) ? n0 : (jj == 1) ? n1 : (jj == 2) ? n2 : n3;
      float4 w0 = *(const float4*)(wz + (c0 + jj) * 8);
      float4 w1 = *(const float4*)(wz + (c0 + jj) * 8 + 4);
      ph[0] = fmaf(nj, w0.x, ph[0]); ph[1] = fmaf(nj, w0.y, ph[1]);
      ph[2] = fmaf(nj, w0.z, ph[2]); ph[3] = fmaf(nj, w0.w, ph[3]);
      ph[4] = fmaf(nj, w1.x, ph[4]); ph[5] = fmaf(nj, w1.y, ph[5]);
      ph[6] = fmaf(nj, w1.z, ph[6]); ph[7] = fmaf(nj, w1.w, ph[7]);
    }
  }
  // component-splitting reduce over the 8 lanes of the pair (xor 1,2,4)
  float a[4];
#pragma unroll
  for (int j = 0; j < 4; j++) {
    float keep = (l & 1) ? ph[4 + j] : ph[j];
    float send = (l & 1) ? ph[j] : ph[4 + j];
    a[j] = keep + __shfl_xor(send, 1, 64);
  }
  float b2[2];
#pragma unroll
  for (int j = 0; j < 2; j++) {
    float keep = (l & 2) ? a[2 + j] : a[j];
    float send = (l & 2) ? a[j] : a[2 + j];
    b2[j] = keep + __shfl_xor(send, 2, 64);
  }
  float keep = (l & 4) ? b2[1] : b2[0];
  float send = (l & 4) ? b2[0] : b2[1];
  float c = keep + __shfl_xor(send, 4, 64);
  int hh = 4 * (l & 1) + (l & 2) + ((l & 4) >> 2);
  zbb[(size_t)hh * 65536 + op] = f2bb(c * LOG2E);
}

// ---------- kernel 2: LN(m) -> bf16 ----------
__global__ __launch_bounds__(256) void k_lnm(const float* __restrict__ m,
                                             const float* __restrict__ g,
                                             const float* __restrict__ b,
                                             u16* __restrict__ mln) {
  int w = threadIdx.x >> 6, lane = threadIdx.x & 63;
  size_t row = (size_t)blockIdx.x * 4 + w;
  const float4 v = *(const float4*)(m + row * 256 + lane * 4);
  float sum = wsum(v.x + v.y + v.z + v.w);
  float ssq = wsum(v.x * v.x + v.y * v.y + v.z * v.z + v.w * v.w);
  float mu = sum * (1.f / 256);
  float rs = rsqrtf(ssq * (1.f / 256) - mu * mu + 1e-5f);
  const float4 gg = *(const float4*)(g + lane * 4);
  const float4 bb = *(const float4*)(b + lane * 4);
  ushort4 o;
  o.x = f2bb((v.x - mu) * rs * gg.x + bb.x);
  o.y = f2bb((v.y - mu) * rs * gg.y + bb.y);
  o.z = f2bb((v.z - mu) * rs * gg.z + bb.z);
  o.w = f2bb((v.w - mu) * rs * gg.w + bb.w);
  *(ushort4*)(mln + row * 256 + lane * 4) = o;
}

// ---------- kernel 3: 128x128-tile MFMA GEMM  mln @ Wcat -> q/k/vt/g ----------
__global__ __launch_bounds__(256) void k_proj(const u16* __restrict__ mln,
                                              const u16* __restrict__ wcat_t,
                                              const float* __restrict__ bg,
                                              u16* __restrict__ qb,
                                              u16* __restrict__ kbuf,
                                              u16* __restrict__ vt,
                                              u16* __restrict__ gb) {
  __shared__ __align__(16) u16 lds[4 * 8192];  // A0 A1 B0 B1 (16KB each)
  int tid = threadIdx.x;
  int w = tid >> 6, l = tid & 63;
  int l15 = l & 15, lg = l >> 4;
  int wr = w >> 1, wc = w & 1;
  int grow0 = blockIdx.x * 128;
  int hdt0 = blockIdx.y * 128;
  const u16* asrc = mln + (size_t)grow0 * 256;
  const u16* bsrc = wcat_t + (size_t)hdt0 * 256;

  stage_tile(asrc, lds, w, l);
  stage_tile(bsrc, lds + 16384, w, l);
  __syncthreads();

  f32x4 acc[4][4];
#pragma unroll
  for (int mi = 0; mi < 4; mi++)
#pragma unroll
    for (int ni = 0; ni < 4; ni++) acc[mi][ni] = (f32x4){0.f, 0.f, 0.f, 0.f};

#pragma unroll
  for (int kt = 0; kt < 4; kt++) {
    if (kt < 3) {
      stage_tile(asrc + (kt + 1) * 64, lds + ((kt + 1) & 1) * 8192, w, l);
      stage_tile(bsrc + (kt + 1) * 64, lds + 16384 + ((kt + 1) & 1) * 8192, w, l);
    }
    const u16* Ab = lds + (kt & 1) * 8192;
    const u16* Bb = lds + 16384 + (kt & 1) * 8192;
#pragma unroll
    for (int ks = 0; ks < 2; ks++) {
      short8 af[4], bf[4];
#pragma unroll
      for (int i = 0; i < 4; i++) {
        int ra = wr * 64 + i * 16 + l15;
        af[i] = *(const short8*)(Ab + ra * 64 + (((ks * 4 + lg) ^ (ra & 7)) << 3));
        int rb = wc * 64 + i * 16 + l15;
        bf[i] = *(const short8*)(Bb + rb * 64 + (((ks * 4 + lg) ^ (rb & 7)) << 3));
      }
#pragma unroll
      for (int mi = 0; mi < 4; mi++)
#pragma unroll
        for (int ni = 0; ni < 4; ni++)
          acc[mi][ni] =
              __builtin_amdgcn_mfma_f32_16x16x32_bf16(af[mi], bf[ni], acc[mi][ni], 0, 0, 0);
    }
    __syncthreads();
  }

  // ---- epilogue: re-stage through LDS for coalesced uint4 stores ----
  int by = blockIdx.y;
  int mat = by >> 1;            // 0:q 1:k 2:v(transposed) 3:g
  int s = grow0 >> 8, r0 = grow0 & 255;
  int hbase = (by & 1) * 128;
  u16* stg = lds;               // [128][136] bf16

  if (mat == 2) {
#pragma unroll
    for (int mi = 0; mi < 4; mi++)
#pragma unroll
      for (int ni = 0; ni < 4; ni++)
#pragma unroll
        for (int j = 0; j < 4; j++) {
          int rl = wr * 64 + mi * 16 + lg * 4 + j;
          int hl = wc * 64 + ni * 16 + l15;
          stg[hl * 136 + rl] = f2bb(acc[mi][ni][j]);
        }
    __syncthreads();
#pragma unroll
    for (int it = 0; it < 8; it++) {
      int idx = it * 256 + tid;
      int dl = idx >> 4, c = idx & 15;
      int hd = hbase + dl;
      uint4 val = *(const uint4*)(stg + dl * 136 + c * 8);
      *(uint4*)(vt + ((size_t)(s * 8 + (hd >> 5)) * 32 + (hd & 31)) * 256 + r0 + c * 8) = val;
    }
  } else {
    float bgv[4];
    if (mat == 3) {
#pragma unroll
      for (int ni = 0; ni < 4; ni++) bgv[ni] = bg[hbase + wc * 64 + ni * 16 + l15];
    }
#pragma unroll
    for (int mi = 0; mi < 4; mi++)
#pragma unroll
      for (int ni = 0; ni < 4; ni++)
#pragma unroll
        for (int j = 0; j < 4; j++) {
          int rl = wr * 64 + mi * 16 + lg * 4 + j;
          int hl = wc * 64 + ni * 16 + l15;
          float v = acc[mi][ni][j];
          if (mat == 3) v = 1.0f / (1.0f + __expf(-(v + bgv[ni])));
          stg[rl * 136 + hl] = f2bb(v);
        }
    __syncthreads();
#pragma unroll
    for (int it = 0; it < 8; it++) {
      int idx = it * 256 + tid;
      int rl = idx >> 4, c = idx & 15;
      uint4 val = *(const uint4*)(stg + rl * 136 + c * 8);
      int hd = hbase + c * 8;
      if (mat == 3) {
        *(uint4*)(gb + (size_t)(grow0 + rl) * 256 + hd) = val;
      } else {
        u16* dst = (mat == 0) ? qb : kbuf;
        *(uint4*)(dst + ((size_t)(s * 8 + (hd >> 5)) * 256 + r0 + rl) * 32 + (hd & 31)) = val;
      }
    }
  }
}

// ---------- kernel 4: swapped-QK 32x32 MFMA flash attention, register softmax ----------
// Per (s,h): 4 waves x 64 q-rows. Swapped QK^T (A=K, B=Q) puts q on lane&31:
// softmax is per-lane + one shfl_xor(32). P -> PV A-frag via cvt_pk + permlane32_swap.
__global__ __launch_bounds__(256, 4) void k_attn(const u16* __restrict__ qb,
                                                 const u16* __restrict__ kbuf,
                                                 const u16* __restrict__ vt,
                                                 const u16* __restrict__ gb,
                                                 const u16* __restrict__ zbb,
                                                 const float* __restrict__ mask,
                                                 u16* __restrict__ og) {
  int blk = blockIdx.x;
  int s = blk >> 3, h = blk & 7;
  int tid = threadIdx.x, w = tid >> 6, l = tid & 63;
  int l31 = l & 31, l5 = l >> 5;
  int q0 = w * 64;
  size_t base = (size_t)(s * 8 + h) * 256 * 32;
  const u16* zrow = zbb + (size_t)h * 65536;   // [q][col] bf16, log2e folded
  const float* mrow = mask + s * 256;

  // Q B-frags: Q[q0+qt*32+l31][dh*16 + l5*8 ..+7]
  short8 qf[2][2];
#pragma unroll
  for (int qt = 0; qt < 2; qt++)
#pragma unroll
    for (int dh = 0; dh < 2; dh++)
      qf[qt][dh] = *(const short8*)(qb + base + (size_t)(q0 + qt * 32 + l31) * 32 +
                                    dh * 16 + l5 * 8);

  f32x16 oacc[2];
#pragma unroll
  for (int qt = 0; qt < 2; qt++)
#pragma unroll
    for (int j = 0; j < 16; j++) oacc[qt][j] = 0.f;
  float ls0[2] = {0.f, 0.f}, ls1[2] = {0.f, 0.f};

#pragma unroll
  for (int kb = 0; kb < 4; kb++) {
    int kbase = kb * 64;
    // K A-frags: K[kbase+kt*32+l31][dh*16 + l5*8..]
    short8 kf[2][2];
#pragma unroll
    for (int kt = 0; kt < 2; kt++)
#pragma unroll
      for (int dh = 0; dh < 2; dh++)
        kf[kt][dh] = *(const short8*)(kbuf + base + (size_t)(kbase + kt * 32 + l31) * 32 +
                                      dh * 16 + l5 * 8);
    // V B-frags: V[kbase+kt*32+ks*16+l5*8..][d=l31] from vt[d][r]
    short8 vf[2][2];
#pragma unroll
    for (int kt = 0; kt < 2; kt++)
#pragma unroll
      for (int ks = 0; ks < 2; ks++)
        vf[kt][ks] = *(const short8*)(vt + base + (size_t)l31 * 256 + kbase + kt * 32 +
                                      ks * 16 + l5 * 8);

#pragma unroll
    for (int qt = 0; qt < 2; qt++) {
      int q = q0 + qt * 32 + l31;
      const u16* zq = zrow + (size_t)q * 256 + kbase;
#pragma unroll
      for (int kt = 0; kt < 2; kt++) {
        // ---- C-init = log2e*(z + 1e9*(mask-1)); k rows per reg: crow = (j&3)+8*(j>>2)+4*l5
        f32x16 c;
#pragma unroll
        for (int cc = 0; cc < 4; cc++) {
          ushort4 zu = *(const ushort4*)(zq + kt * 32 + cc * 8 + l5 * 4);
          float4 mv = *(const float4*)(mrow + kbase + kt * 32 + cc * 8 + l5 * 4);
          c[4 * cc + 0] = b2f(zu.x) + (LOG2E * 1e9f) * (mv.x - 1.0f);
          c[4 * cc + 1] = b2f(zu.y) + (LOG2E * 1e9f) * (mv.y - 1.0f);
          c[4 * cc + 2] = b2f(zu.z) + (LOG2E * 1e9f) * (mv.z - 1.0f);
          c[4 * cc + 3] = b2f(zu.w) + (LOG2E * 1e9f) * (mv.w - 1.0f);
        }
        // ---- S^T = K @ Q^T + C  (lane: col=q, rows=k)
        c = __builtin_amdgcn_mfma_f32_32x32x16_bf16(kf[kt][0], qf[qt][0], c, 0, 0, 0);
        c = __builtin_amdgcn_mfma_f32_32x32x16_bf16(kf[kt][1], qf[qt][1], c, 0, 0, 0);
        // ---- p = exp2(c); row-sum partials
        float p[16];
#pragma unroll
        for (int j = 0; j < 16; j++) {
          p[j] = __builtin_amdgcn_exp2f(c[j]);
          if (j & 1) ls1[qt] += p[j]; else ls0[qt] += p[j];
        }
        // ---- pack to bf16 words (compiler-managed cvt_pk + permlane -> hazards handled)
        unsigned wd[8];
#pragma unroll
        for (int r = 0; r < 8; r++) wd[r] = pkbf16(p[2 * r], p[2 * r + 1]);
        {
          uint2v r0 = __builtin_amdgcn_permlane32_swap(wd[0], wd[2], false, false);
          wd[0] = r0[0]; wd[2] = r0[1];
          uint2v r1 = __builtin_amdgcn_permlane32_swap(wd[1], wd[3], false, false);
          wd[1] = r1[0]; wd[3] = r1[1];
          uint2v r2 = __builtin_amdgcn_permlane32_swap(wd[4], wd[6], false, false);
          wd[4] = r2[0]; wd[6] = r2[1];
          uint2v r3 = __builtin_amdgcn_permlane32_swap(wd[5], wd[7], false, false);
          wd[5] = r3[0]; wd[7] = r3[1];
        }
        union { unsigned u[4]; short8 s8; } pa0, pa1;
        pa0.u[0] = wd[0]; pa0.u[1] = wd[1]; pa0.u[2] = wd[2]; pa0.u[3] = wd[3];
        pa1.u[0] = wd[4]; pa1.u[1] = wd[5]; pa1.u[2] = wd[6]; pa1.u[3] = wd[7];
        // ---- O[q][d] += P @ V
        oacc[qt] = __builtin_amdgcn_mfma_f32_32x32x16_bf16(pa0.s8, vf[kt][0], oacc[qt], 0, 0, 0);
        oacc[qt] = __builtin_amdgcn_mfma_f32_32x32x16_bf16(pa1.s8, vf[kt][1], oacc[qt], 0, 0, 0);
      }
    }
  }
  // ---- finalize row sums (lane holds q=l31; halves hold disjoint k-sets)
  float inv[2];
#pragma unroll
  for (int qt = 0; qt < 2; qt++) {
    float v = ls0[qt] + ls1[qt];
    v += __shfl_xor(v, 32, 64);
    inv[qt] = 1.0f / v;
  }
  // ---- normalize, gate, store (O layout: col=l31=d, row q = (j&3)+8*(j>>2)+4*l5)
#pragma unroll
  for (int qt = 0; qt < 2; qt++) {
#pragma unroll
    for (int j = 0; j < 16; j++) {
      int qrow = (j & 3) + 8 * (j >> 2) + 4 * l5;
      float invj = __shfl(inv[qt], qrow, 64);
      int q = q0 + qt * 32 + qrow;
      size_t ob = ((size_t)s * 256 + q) * 256 + h * 32 + l31;
      float gv = b2f(gb[ob]);
      og[ob] = f2bb(oacc[qt][j] * invj * gv);
    }
  }
}

// ---------- kernel 5: 128x128-tile MFMA GEMM  og @ WO + bo -> out f32 ----------
__global__ __launch_bounds__(256) void k_out(const u16* __restrict__ og,
                                             const u16* __restrict__ wot,
                                             const float* __restrict__ bo,
                                             float* __restrict__ out) {
  __shared__ __align__(16) u16 lds[4 * 8192];
  int tid = threadIdx.x;
  int w = tid >> 6, l = tid & 63;
  int l15 = l & 15, lg = l >> 4;
  int wr = w >> 1, wc = w & 1;
  int grow0 = blockIdx.x * 128;
  int ct0 = blockIdx.y * 128;
  const u16* asrc = og + (size_t)grow0 * 256;
  const u16* bsrc = wot + (size_t)ct0 * 256;

  stage_tile(asrc, lds, w, l);
  stage_tile(bsrc, lds + 16384, w, l);
  __syncthreads();

  f32x4 acc[4][4];
#pragma unroll
  for (int mi = 0; mi < 4; mi++)
#pragma unroll
    for (int ni = 0; ni < 4; ni++) acc[mi][ni] = (f32x4){0.f, 0.f, 0.f, 0.f};

#pragma unroll
  for (int kt = 0; kt < 4; kt++) {
    if (kt < 3) {
      stage_tile(asrc + (kt + 1) * 64, lds + ((kt + 1) & 1) * 8192, w, l);
      stage_tile(bsrc + (kt + 1) * 64, lds + 16384 + ((kt + 1) & 1) * 8192, w, l);
    }
    const u16* Ab = lds + (kt & 1) * 8192;
    const u16* Bb = lds + 16384 + (kt & 1) * 8192;
#pragma unroll
    for (int ks = 0; ks < 2; ks++) {
      short8 af[4], bf[4];
#pragma unroll
      for (int i = 0; i < 4; i++) {
        int ra = wr * 64 + i * 16 + l15;
        af[i] = *(const short8*)(Ab + ra * 64 + (((ks * 4 + lg) ^ (ra & 7)) << 3));
        int rb = wc * 64 + i * 16 + l15;
        bf[i] = *(const short8*)(Bb + rb * 64 + (((ks * 4 + lg) ^ (rb & 7)) << 3));
      }
#pragma unroll
      for (int mi = 0; mi < 4; mi++)
#pragma unroll
        for (int ni = 0; ni < 4; ni++)
          acc[mi][ni] =
              __builtin_amdgcn_mfma_f32_16x16x32_bf16(af[mi], bf[ni], acc[mi][ni], 0, 0, 0);
    }
    __syncthreads();
  }

  int cout_base = ct0 + wc * 64;
#pragma unroll
  for (int ni = 0; ni < 4; ni++) {
    int cout = cout_base + ni * 16 + l15;
    float bov = bo[cout];
#pragma unroll
    for (int mi = 0; mi < 4; mi++)
#pragma unroll
      for (int j = 0; j < 4; j++)
        out[(size_t)(grow0 + wr * 64 + mi * 16 + lg * 4 + j) * 256 + cout] =
            acc[mi][ni][j] + bov;
  }
}

extern "C" void kernel_launch(void* const* d_in, const int* in_sizes, int n_in,
                              void* d_out, int out_size, void* d_ws, size_t ws_size,
                              hipStream_t stream) {
  const float* m      = (const float*)d_in[0];
  const float* z      = (const float*)d_in[1];
  const float* mask   = (const float*)d_in[2];
  const float* ln_m_g = (const float*)d_in[3];
  const float* ln_m_b = (const float*)d_in[4];
  const float* ln_z_g = (const float*)d_in[5];
  const float* ln_z_b = (const float*)d_in[6];
  const float* wz     = (const float*)d_in[7];
  const float* wq     = (const float*)d_in[8];
  const float* wk     = (const float*)d_in[9];
  const float* wv     = (const float*)d_in[10];
  const float* wg     = (const float*)d_in[11];
  const float* bg     = (const float*)d_in[12];
  const float* wo     = (const float*)d_in[13];
  const float* bo     = (const float*)d_in[14];
  float* out = (float*)d_out;

  char* ws = (char*)d_ws;
  const size_t MiB = 1u << 20;
  u16* zbb     = (u16*)(ws);                        // 1 MiB  [h][q*256+col] bf16
  u16* wcat_t  = (u16*)(ws + 2 * MiB);              // 512 KiB
  u16* wot     = (u16*)(ws + 2 * MiB + 512 * 1024); // 128 KiB
  u16* mln     = (u16*)(ws + 3 * MiB);              // 16 MiB
  u16* qb      = (u16*)(ws + 19 * MiB);             // 16 MiB  [s][h][r][d]
  u16* kb      = (u16*)(ws + 35 * MiB);             // 16 MiB  [s][h][r][d]
  u16* vt      = (u16*)(ws + 51 * MiB);             // 16 MiB  [s][h][d][r]
  u16* gb      = (u16*)(ws + 67 * MiB);             // 16 MiB  [row][hd]
  u16* ogb     = (u16*)(ws + 83 * MiB);             // 16 MiB  [row][hd]
  (void)in_sizes; (void)n_in; (void)out_size; (void)ws_size;

  k_prep<<<dim3(16, 5), 256, 0, stream>>>(wq, wk, wv, wg, wo, wcat_t, wot);
  k_zbias<<<(R * R) / 32, 256, 0, stream>>>(z, ln_z_g, ln_z_b, wz, zbb);
  k_lnm<<<(S * R) / 4, 256, 0, stream>>>(m, ln_m_g, ln_m_b, mln);
  k_proj<<<dim3(256, 8), 256, 0, stream>>>(mln, wcat_t, bg, qb, kb, vt, gb);
  k_attn<<<S * H, 256, 0, stream>>>(qb, kb, vt, gb, zbb, mask, ogb);
  k_out<<<dim3(256, 2), 256, 0, stream>>>(ogb, wot, bo, out);
}

// Round 9
// 331.521 us; speedup vs baseline: 1.0344x; 1.0344x over previous
//
#include <hip/hip_runtime.h>
#include <hip/hip_bf16.h>
#include <stdint.h>

#define S 128
#define R 256
#define CM 256
#define CZ 128
#define H 8
#define D 32

typedef __attribute__((ext_vector_type(8))) short short8;
typedef __attribute__((ext_vector_type(4))) float f32x4;
typedef __attribute__((ext_vector_type(16))) float f32x16;
typedef __attribute__((ext_vector_type(2))) unsigned uint2v;
typedef unsigned short u16;

#define LOG2E 1.4426950408889634f

// ---------- helpers ----------
__device__ __forceinline__ float wsum(float v) {
#pragma unroll
  for (int o = 32; o > 0; o >>= 1) v += __shfl_xor(v, o, 64);
  return v;
}
__device__ __forceinline__ u16 f2bb(float f) {
  unsigned u = __float_as_uint(f);
  return (u16)((u + 0x7fffu + ((u >> 16) & 1u)) >> 16);
}
__device__ __forceinline__ float b2f(u16 u) {
  return __uint_as_float(((unsigned)u) << 16);
}
__device__ __forceinline__ unsigned pkbf16(float a, float b) {
  __hip_bfloat162 t = __float22bfloat162_rn(make_float2(a, b));
  union { __hip_bfloat162 h; unsigned u; } cv;
  cv.h = t;
  return cv.u;
}
__device__ __forceinline__ void gl_lds16(const u16* g, u16* l) {
  __builtin_amdgcn_global_load_lds(
      (const __attribute__((address_space(1))) unsigned int*)g,
      (__attribute__((address_space(3))) unsigned int*)l, 16, 0, 0);
}

// stage a [128 rows][64 cols] bf16 tile (src row stride 256 elems) into linear LDS.
__device__ __forceinline__ void stage_tile(const u16* __restrict__ src, u16* lbase,
                                           int w, int l) {
#pragma unroll
  for (int it = 0; it < 4; it++) {
    int rbase = it * 32 + w * 8;
    int row = rbase + (l >> 3);
    int gc8 = (l & 7) ^ (row & 7);
    gl_lds16(src + (size_t)row * 256 + gc8 * 8, lbase + rbase * 64);
  }
}

// ---------- kernel 0: weights -> bf16, transposed [hd'][c]; qscale*log2e folded ----------
__global__ __launch_bounds__(256) void k_prep(const float* __restrict__ wq,
                                              const float* __restrict__ wk,
                                              const float* __restrict__ wv,
                                              const float* __restrict__ wg,
                                              const float* __restrict__ wo,
                                              u16* __restrict__ wcat_t,
                                              u16* __restrict__ wot) {
  __shared__ float t[64][65];
  int mat = blockIdx.y;  // 0..4
  const float* src = (mat == 0) ? wq : (mat == 1) ? wk : (mat == 2) ? wv
                     : (mat == 3) ? wg : wo;
  // q: 1/sqrt(D) * log2(e) folded (softmax uses exp2)
  float scale = (mat == 0) ? 0.17677669529663687f * LOG2E : 1.0f;
  u16* dst = (mat < 4) ? (wcat_t + mat * 256 * 256) : wot;
  int ti = blockIdx.x >> 2, tj = blockIdx.x & 3;
  int tid = threadIdx.x;
  int cc = tid & 63, rr4 = tid >> 6;
#pragma unroll
  for (int it = 0; it < 16; it++) {
    int ic = it * 4 + rr4;
    t[ic][cc] = src[(tj * 64 + ic) * 256 + ti * 64 + cc];
  }
  __syncthreads();
#pragma unroll
  for (int it = 0; it < 16; it++) {
    int oh = it * 4 + rr4;
    dst[(ti * 64 + oh) * 256 + tj * 64 + cc] = f2bb(t[cc][oh] * scale);
  }
}

// ---------- kernel 1: pair bias -> bf16 TRANSPOSED zbb[h][col*256+q], log2e folded ----------
// Reads z row-major (coalesced); only the 1MB of final stores are scattered.
__global__ __launch_bounds__(256) void k_zbias(const float* __restrict__ z,
                                               const float* __restrict__ lng,
                                               const float* __restrict__ lnb,
                                               const float* __restrict__ wz,
                                               u16* __restrict__ zbb) {
  int tid = threadIdx.x;
  int l = tid & 63, w = tid >> 6;
  int psub = l >> 3, cg = l & 7;
  int op = blockIdx.x * 32 + w * 8 + psub;   // op = q*256 + col (z pair index)
  const float* zr = z + (size_t)op * CZ;
  float4 v[4];
#pragma unroll
  for (int i = 0; i < 4; i++) v[i] = *(const float4*)(zr + i * 32 + cg * 4);
  float sum = 0.f, ssq = 0.f;
#pragma unroll
  for (int i = 0; i < 4; i++) {
    sum += v[i].x + v[i].y + v[i].z + v[i].w;
    ssq += v[i].x * v[i].x + v[i].y * v[i].y + v[i].z * v[i].z + v[i].w * v[i].w;
  }
  sum += __shfl_xor(sum, 1, 64); sum += __shfl_xor(sum, 2, 64); sum += __shfl_xor(sum, 4, 64);
  ssq += __shfl_xor(ssq, 1, 64); ssq += __shfl_xor(ssq, 2, 64); ssq += __shfl_xor(ssq, 4, 64);
  float mu = sum * (1.0f / CZ);
  float rs = rsqrtf(ssq * (1.0f / CZ) - mu * mu + 1e-5f);
  float ph[8];
#pragma unroll
  for (int hh = 0; hh < 8; hh++) ph[hh] = 0.f;
#pragma unroll
  for (int i = 0; i < 4; i++) {
    int c0 = i * 32 + cg * 4;
    float4 gg = *(const float4*)(lng + c0);
    float4 bb = *(const float4*)(lnb + c0);
    float n0 = (v[i].x - mu) * rs * gg.x + bb.x;
    float n1 = (v[i].y - mu) * rs * gg.y + bb.y;
    float n2 = (v[i].z - mu) * rs * gg.z + bb.z;
    float n3 = (v[i].w - mu) * rs * gg.w + bb.w;
#pragma unroll
    for (int jj = 0; jj < 4; jj++) {
      float nj = (jj == 0) ? n0 : (jj == 1) ? n1 : (jj == 2) ? n2 : n3;
      float4 w0 = *(const float4*)(wz + (c0 + jj) * 8);
      float4 w1 = *(const float4*)(wz + (c0 + jj) * 8 + 4);
      ph[0] = fmaf(nj, w0.x, ph[0]); ph[1] = fmaf(nj, w0.y, ph[1]);
      ph[2] = fmaf(nj, w0.z, ph[2]); ph[3] = fmaf(nj, w0.w, ph[3]);
      ph[4] = fmaf(nj, w1.x, ph[4]); ph[5] = fmaf(nj, w1.y, ph[5]);
      ph[6] = fmaf(nj, w1.z, ph[6]); ph[7] = fmaf(nj, w1.w, ph[7]);
    }
  }
  // component-splitting reduce over the 8 lanes of the pair (xor 1,2,4)
  float a[4];
#pragma unroll
  for (int j = 0; j < 4; j++) {
    float keep = (l & 1) ? ph[4 + j] : ph[j];
    float send = (l & 1) ? ph[j] : ph[4 + j];
    a[j] = keep + __shfl_xor(send, 1, 64);
  }
  float b2[2];
#pragma unroll
  for (int j = 0; j < 2; j++) {
    float keep = (l & 2) ? a[2 + j] : a[j];
    float send = (l & 2) ? a[j] : a[2 + j];
    b2[j] = keep + __shfl_xor(send, 2, 64);
  }
  float keep = (l & 4) ? b2[1] : b2[0];
  float send = (l & 4) ? b2[0] : b2[1];
  float c = keep + __shfl_xor(send, 4, 64);
  int hh = 4 * (l & 1) + (l & 2) + ((l & 4) >> 2);
  // transposed store: [h][col*256 + q]
  zbb[(size_t)hh * 65536 + (size_t)(op & 255) * 256 + (op >> 8)] = f2bb(c * LOG2E);
}

// ---------- kernel 2: LN(m) -> bf16 ----------
__global__ __launch_bounds__(256) void k_lnm(const float* __restrict__ m,
                                             const float* __restrict__ g,
                                             const float* __restrict__ b,
                                             u16* __restrict__ mln) {
  int w = threadIdx.x >> 6, lane = threadIdx.x & 63;
  size_t row = (size_t)blockIdx.x * 4 + w;
  const float4 v = *(const float4*)(m + row * 256 + lane * 4);
  float sum = wsum(v.x + v.y + v.z + v.w);
  float ssq = wsum(v.x * v.x + v.y * v.y + v.z * v.z + v.w * v.w);
  float mu = sum * (1.f / 256);
  float rs = rsqrtf(ssq * (1.f / 256) - mu * mu + 1e-5f);
  const float4 gg = *(const float4*)(g + lane * 4);
  const float4 bb = *(const float4*)(b + lane * 4);
  ushort4 o;
  o.x = f2bb((v.x - mu) * rs * gg.x + bb.x);
  o.y = f2bb((v.y - mu) * rs * gg.y + bb.y);
  o.z = f2bb((v.z - mu) * rs * gg.z + bb.z);
  o.w = f2bb((v.w - mu) * rs * gg.w + bb.w);
  *(ushort4*)(mln + row * 256 + lane * 4) = o;
}

// ---------- kernel 3: 128x128-tile MFMA GEMM  mln @ Wcat -> q/k/vfrag/g ----------
__global__ __launch_bounds__(256) void k_proj(const u16* __restrict__ mln,
                                              const u16* __restrict__ wcat_t,
                                              const float* __restrict__ bg,
                                              u16* __restrict__ qb,
                                              u16* __restrict__ kbuf,
                                              u16* __restrict__ vt,
                                              u16* __restrict__ gb) {
  __shared__ __align__(16) u16 lds[4 * 8192];  // A0 A1 B0 B1 (16KB each)
  int tid = threadIdx.x;
  int w = tid >> 6, l = tid & 63;
  int l15 = l & 15, lg = l >> 4;
  int wr = w >> 1, wc = w & 1;
  int grow0 = blockIdx.x * 128;
  int hdt0 = blockIdx.y * 128;
  const u16* asrc = mln + (size_t)grow0 * 256;
  const u16* bsrc = wcat_t + (size_t)hdt0 * 256;

  stage_tile(asrc, lds, w, l);
  stage_tile(bsrc, lds + 16384, w, l);
  __syncthreads();

  f32x4 acc[4][4];
#pragma unroll
  for (int mi = 0; mi < 4; mi++)
#pragma unroll
    for (int ni = 0; ni < 4; ni++) acc[mi][ni] = (f32x4){0.f, 0.f, 0.f, 0.f};

#pragma unroll
  for (int kt = 0; kt < 4; kt++) {
    if (kt < 3) {
      stage_tile(asrc + (kt + 1) * 64, lds + ((kt + 1) & 1) * 8192, w, l);
      stage_tile(bsrc + (kt + 1) * 64, lds + 16384 + ((kt + 1) & 1) * 8192, w, l);
    }
    const u16* Ab = lds + (kt & 1) * 8192;
    const u16* Bb = lds + 16384 + (kt & 1) * 8192;
#pragma unroll
    for (int ks = 0; ks < 2; ks++) {
      short8 af[4], bf[4];
#pragma unroll
      for (int i = 0; i < 4; i++) {
        int ra = wr * 64 + i * 16 + l15;
        af[i] = *(const short8*)(Ab + ra * 64 + (((ks * 4 + lg) ^ (ra & 7)) << 3));
        int rb = wc * 64 + i * 16 + l15;
        bf[i] = *(const short8*)(Bb + rb * 64 + (((ks * 4 + lg) ^ (rb & 7)) << 3));
      }
#pragma unroll
      for (int mi = 0; mi < 4; mi++)
#pragma unroll
        for (int ni = 0; ni < 4; ni++)
          acc[mi][ni] =
              __builtin_amdgcn_mfma_f32_16x16x32_bf16(af[mi], bf[ni], acc[mi][ni], 0, 0, 0);
    }
    __syncthreads();
  }

  // ---- epilogue: re-stage through LDS for coalesced uint4 stores ----
  int by = blockIdx.y;
  int mat = by >> 1;            // 0:q 1:k 2:v(frag layout) 3:g
  int s = grow0 >> 8, r0 = grow0 & 255;
  int hbase = (by & 1) * 128;
  u16* stg = lds;               // [128][136] bf16

  if (mat == 2) {
    // stage transposed: stg[hd_loc][k_loc]
#pragma unroll
    for (int mi = 0; mi < 4; mi++)
#pragma unroll
      for (int ni = 0; ni < 4; ni++)
#pragma unroll
        for (int j = 0; j < 4; j++) {
          int rl = wr * 64 + mi * 16 + lg * 4 + j;
          int hl = wc * 64 + ni * 16 + l15;
          stg[hl * 136 + rl] = f2bb(acc[mi][ni][j]);
        }
    __syncthreads();
    // frag layout: vt[((s*8+h)*16 + k16)*512 + l5*256 + d*8 + (k&7)]
#pragma unroll
    for (int it = 0; it < 8; it++) {
      int idx = it * 256 + tid;
      int hd_l = idx & 127, k8 = idx >> 7;      // k8: 0..15 (8-element k chunk)
      uint4 val = *(const uint4*)(stg + hd_l * 136 + k8 * 8);
      int hd = hbase + hd_l;
      int h = hd >> 5, d = hd & 31;
      int kg = r0 + k8 * 8;
      size_t off = (((size_t)(s * 8 + h) * 16 + (kg >> 4)) * 2 + ((kg >> 3) & 1)) * 256 + d * 8;
      *(uint4*)(vt + off) = val;
    }
  } else {
    float bgv[4];
    if (mat == 3) {
#pragma unroll
      for (int ni = 0; ni < 4; ni++) bgv[ni] = bg[hbase + wc * 64 + ni * 16 + l15];
    }
#pragma unroll
    for (int mi = 0; mi < 4; mi++)
#pragma unroll
      for (int ni = 0; ni < 4; ni++)
#pragma unroll
        for (int j = 0; j < 4; j++) {
          int rl = wr * 64 + mi * 16 + lg * 4 + j;
          int hl = wc * 64 + ni * 16 + l15;
          float v = acc[mi][ni][j];
          if (mat == 3) v = 1.0f / (1.0f + __expf(-(v + bgv[ni])));
          stg[rl * 136 + hl] = f2bb(v);
        }
    __syncthreads();
#pragma unroll
    for (int it = 0; it < 8; it++) {
      int idx = it * 256 + tid;
      int rl = idx >> 4, c = idx & 15;
      uint4 val = *(const uint4*)(stg + rl * 136 + c * 8);
      int hd = hbase + c * 8;
      if (mat == 3) {
        *(uint4*)(gb + (size_t)(grow0 + rl) * 256 + hd) = val;
      } else {
        u16* dst = (mat == 0) ? qb : kbuf;
        *(uint4*)(dst + ((size_t)(s * 8 + (hd >> 5)) * 256 + r0 + rl) * 32 + (hd & 31)) = val;
      }
    }
  }
}

// ---------- kernel 4: swapped-QK 32x32 MFMA flash attention, register softmax ----------
__global__ __launch_bounds__(256, 3) void k_attn(const u16* __restrict__ qb,
                                                 const u16* __restrict__ kbuf,
                                                 const u16* __restrict__ vt,
                                                 const u16* __restrict__ gb,
                                                 const u16* __restrict__ zbb,
                                                 const float* __restrict__ mask,
                                                 u16* __restrict__ og) {
  int blk = blockIdx.x;
  int s = blk >> 3, h = blk & 7;
  int tid = threadIdx.x, w = tid >> 6, l = tid & 63;
  int l31 = l & 31, l5 = l >> 5;
  int q0 = w * 64;
  size_t base = (size_t)(s * 8 + h) * 256 * 32;
  const u16* zcol = zbb + (size_t)h * 65536;   // [col][q] bf16, log2e folded
  const float* mrow = mask + s * 256;

  // Q B-frags: Q[q0+qt*32+l31][dh*16 + l5*8 ..+7]
  short8 qf[2][2];
#pragma unroll
  for (int qt = 0; qt < 2; qt++)
#pragma unroll
    for (int dh = 0; dh < 2; dh++)
      qf[qt][dh] = *(const short8*)(qb + base + (size_t)(q0 + qt * 32 + l31) * 32 +
                                    dh * 16 + l5 * 8);

  f32x16 oacc[2];
#pragma unroll
  for (int qt = 0; qt < 2; qt++)
#pragma unroll
    for (int j = 0; j < 16; j++) oacc[qt][j] = 0.f;
  float ls0[2] = {0.f, 0.f}, ls1[2] = {0.f, 0.f};

#pragma unroll
  for (int kb = 0; kb < 4; kb++) {
    int kbase = kb * 64;
    // K A-frags: K[kbase+kt*32+l31][dh*16 + l5*8..]
    short8 kf[2][2];
#pragma unroll
    for (int kt = 0; kt < 2; kt++)
#pragma unroll
      for (int dh = 0; dh < 2; dh++)
        kf[kt][dh] = *(const short8*)(kbuf + base + (size_t)(kbase + kt * 32 + l31) * 32 +
                                      dh * 16 + l5 * 8);
    // V B-frags from frag layout: fully coalesced (16B/lane)
    short8 vf[2][2];
#pragma unroll
    for (int kt = 0; kt < 2; kt++)
#pragma unroll
      for (int ks = 0; ks < 2; ks++)
        vf[kt][ks] = *(const short8*)(vt + ((size_t)(s * 8 + h) * 16 +
                                            (kb * 4 + kt * 2 + ks)) * 512 +
                                      l5 * 256 + l31 * 8);
    // mask bias per k-col (broadcast loads, shared by all lanes with same l5)
    float mb[2][16];
#pragma unroll
    for (int kt = 0; kt < 2; kt++)
#pragma unroll
      for (int cc = 0; cc < 4; cc++) {
        float4 mv = *(const float4*)(mrow + kbase + kt * 32 + cc * 8 + l5 * 4);
        mb[kt][4 * cc + 0] = (LOG2E * 1e9f) * (mv.x - 1.0f);
        mb[kt][4 * cc + 1] = (LOG2E * 1e9f) * (mv.y - 1.0f);
        mb[kt][4 * cc + 2] = (LOG2E * 1e9f) * (mv.z - 1.0f);
        mb[kt][4 * cc + 3] = (LOG2E * 1e9f) * (mv.w - 1.0f);
      }

#pragma unroll
    for (int qt = 0; qt < 2; qt++) {
      int q = q0 + qt * 32 + l31;
#pragma unroll
      for (int kt = 0; kt < 2; kt++) {
        // ---- C-init = z^T[col][q] + maskbias; reg j of cc: col = kt*32+cc*8+l5*4+j
        f32x16 c;
#pragma unroll
        for (int cc = 0; cc < 4; cc++) {
          const u16* zp = zcol + (size_t)(kbase + kt * 32 + cc * 8 + l5 * 4) * 256 + q;
#pragma unroll
          for (int j = 0; j < 4; j++)
            c[4 * cc + j] = b2f(zp[j * 256]) + mb[kt][4 * cc + j];
        }
        // ---- S^T = K @ Q^T + C  (lane: col=q, rows=k)
        c = __builtin_amdgcn_mfma_f32_32x32x16_bf16(kf[kt][0], qf[qt][0], c, 0, 0, 0);
        c = __builtin_amdgcn_mfma_f32_32x32x16_bf16(kf[kt][1], qf[qt][1], c, 0, 0, 0);
        // ---- p = exp2(c); row-sum partials
        float p[16];
#pragma unroll
        for (int j = 0; j < 16; j++) {
          p[j] = __builtin_amdgcn_exp2f(c[j]);
          if (j & 1) ls1[qt] += p[j]; else ls0[qt] += p[j];
        }
        // ---- pack to bf16 words (compiler-managed cvt_pk + permlane)
        unsigned wd[8];
#pragma unroll
        for (int r = 0; r < 8; r++) wd[r] = pkbf16(p[2 * r], p[2 * r + 1]);
        {
          uint2v r0 = __builtin_amdgcn_permlane32_swap(wd[0], wd[2], false, false);
          wd[0] = r0[0]; wd[2] = r0[1];
          uint2v r1 = __builtin_amdgcn_permlane32_swap(wd[1], wd[3], false, false);
          wd[1] = r1[0]; wd[3] = r1[1];
          uint2v r2 = __builtin_amdgcn_permlane32_swap(wd[4], wd[6], false, false);
          wd[4] = r2[0]; wd[6] = r2[1];
          uint2v r3 = __builtin_amdgcn_permlane32_swap(wd[5], wd[7], false, false);
          wd[5] = r3[0]; wd[7] = r3[1];
        }
        union { unsigned u[4]; short8 s8; } pa0, pa1;
        pa0.u[0] = wd[0]; pa0.u[1] = wd[1]; pa0.u[2] = wd[2]; pa0.u[3] = wd[3];
        pa1.u[0] = wd[4]; pa1.u[1] = wd[5]; pa1.u[2] = wd[6]; pa1.u[3] = wd[7];
        // ---- O[q][d] += P @ V
        oacc[qt] = __builtin_amdgcn_mfma_f32_32x32x16_bf16(pa0.s8, vf[kt][0], oacc[qt], 0, 0, 0);
        oacc[qt] = __builtin_amdgcn_mfma_f32_32x32x16_bf16(pa1.s8, vf[kt][1], oacc[qt], 0, 0, 0);
      }
    }
  }
  // ---- finalize row sums (lane holds q=l31; halves hold disjoint k-sets)
  float inv[2];
#pragma unroll
  for (int qt = 0; qt < 2; qt++) {
    float v = ls0[qt] + ls1[qt];
    v += __shfl_xor(v, 32, 64);
    inv[qt] = 1.0f / v;
  }
  // ---- normalize, gate, store (O layout: col=l31=d, row q = (j&3)+8*(j>>2)+4*l5)
#pragma unroll
  for (int qt = 0; qt < 2; qt++) {
#pragma unroll
    for (int j = 0; j < 16; j++) {
      int qrow = (j & 3) + 8 * (j >> 2) + 4 * l5;
      float invj = __shfl(inv[qt], qrow, 64);
      int q = q0 + qt * 32 + qrow;
      size_t ob = ((size_t)s * 256 + q) * 256 + h * 32 + l31;
      float gv = b2f(gb[ob]);
      og[ob] = f2bb(oacc[qt][j] * invj * gv);
    }
  }
}

// ---------- kernel 5: 128x128-tile MFMA GEMM  og @ WO + bo -> out f32 ----------
__global__ __launch_bounds__(256) void k_out(const u16* __restrict__ og,
                                             const u16* __restrict__ wot,
                                             const float* __restrict__ bo,
                                             float* __restrict__ out) {
  __shared__ __align__(16) u16 lds[4 * 8192];
  int tid = threadIdx.x;
  int w = tid >> 6, l = tid & 63;
  int l15 = l & 15, lg = l >> 4;
  int wr = w >> 1, wc = w & 1;
  int grow0 = blockIdx.x * 128;
  int ct0 = blockIdx.y * 128;
  const u16* asrc = og + (size_t)grow0 * 256;
  const u16* bsrc = wot + (size_t)ct0 * 256;

  stage_tile(asrc, lds, w, l);
  stage_tile(bsrc, lds + 16384, w, l);
  __syncthreads();

  f32x4 acc[4][4];
#pragma unroll
  for (int mi = 0; mi < 4; mi++)
#pragma unroll
    for (int ni = 0; ni < 4; ni++) acc[mi][ni] = (f32x4){0.f, 0.f, 0.f, 0.f};

#pragma unroll
  for (int kt = 0; kt < 4; kt++) {
    if (kt < 3) {
      stage_tile(asrc + (kt + 1) * 64, lds + ((kt + 1) & 1) * 8192, w, l);
      stage_tile(bsrc + (kt + 1) * 64, lds + 16384 + ((kt + 1) & 1) * 8192, w, l);
    }
    const u16* Ab = lds + (kt & 1) * 8192;
    const u16* Bb = lds + 16384 + (kt & 1) * 8192;
#pragma unroll
    for (int ks = 0; ks < 2; ks++) {
      short8 af[4], bf[4];
#pragma unroll
      for (int i = 0; i < 4; i++) {
        int ra = wr * 64 + i * 16 + l15;
        af[i] = *(const short8*)(Ab + ra * 64 + (((ks * 4 + lg) ^ (ra & 7)) << 3));
        int rb = wc * 64 + i * 16 + l15;
        bf[i] = *(const short8*)(Bb + rb * 64 + (((ks * 4 + lg) ^ (rb & 7)) << 3));
      }
#pragma unroll
      for (int mi = 0; mi < 4; mi++)
#pragma unroll
        for (int ni = 0; ni < 4; ni++)
          acc[mi][ni] =
              __builtin_amdgcn_mfma_f32_16x16x32_bf16(af[mi], bf[ni], acc[mi][ni], 0, 0, 0);
    }
    __syncthreads();
  }

  int cout_base = ct0 + wc * 64;
#pragma unroll
  for (int ni = 0; ni < 4; ni++) {
    int cout = cout_base + ni * 16 + l15;
    float bov = bo[cout];
#pragma unroll
    for (int mi = 0; mi < 4; mi++)
#pragma unroll
      for (int j = 0; j < 4; j++)
        out[(size_t)(grow0 + wr * 64 + mi * 16 + lg * 4 + j) * 256 + cout] =
            acc[mi][ni][j] + bov;
  }
}

extern "C" void kernel_launch(void* const* d_in, const int* in_sizes, int n_in,
                              void* d_out, int out_size, void* d_ws, size_t ws_size,
                              hipStream_t stream) {
  const float* m      = (const float*)d_in[0];
  const float* z      = (const float*)d_in[1];
  const float* mask   = (const float*)d_in[2];
  const float* ln_m_g = (const float*)d_in[3];
  const float* ln_m_b = (const float*)d_in[4];
  const float* ln_z_g = (const float*)d_in[5];
  const float* ln_z_b = (const float*)d_in[6];
  const float* wz     = (const float*)d_in[7];
  const float* wq     = (const float*)d_in[8];
  const float* wk     = (const float*)d_in[9];
  const float* wv     = (const float*)d_in[10];
  const float* wg     = (const float*)d_in[11];
  const float* bg     = (const float*)d_in[12];
  const float* wo     = (const float*)d_in[13];
  const float* bo     = (const float*)d_in[14];
  float* out = (float*)d_out;

  char* ws = (char*)d_ws;
  const size_t MiB = 1u << 20;
  u16* zbb     = (u16*)(ws);                        // 1 MiB  [h][col*256+q] bf16
  u16* wcat_t  = (u16*)(ws + 2 * MiB);              // 512 KiB
  u16* wot     = (u16*)(ws + 2 * MiB + 512 * 1024); // 128 KiB
  u16* mln     = (u16*)(ws + 3 * MiB);              // 16 MiB
  u16* qb      = (u16*)(ws + 19 * MiB);             // 16 MiB  [s][h][r][d]
  u16* kb      = (u16*)(ws + 35 * MiB);             // 16 MiB  [s][h][r][d]
  u16* vt      = (u16*)(ws + 51 * MiB);             // 16 MiB  V frag layout
  u16* gb      = (u16*)(ws + 67 * MiB);             // 16 MiB  [row][hd]
  u16* ogb     = (u16*)(ws + 83 * MiB);             // 16 MiB  [row][hd]
  (void)in_sizes; (void)n_in; (void)out_size; (void)ws_size;

  k_prep<<<dim3(16, 5), 256, 0, stream>>>(wq, wk, wv, wg, wo, wcat_t, wot);
  k_zbias<<<(R * R) / 32, 256, 0, stream>>>(z, ln_z_g, ln_z_b, wz, zbb);
  k_lnm<<<(S * R) / 4, 256, 0, stream>>>(m, ln_m_g, ln_m_b, mln);
  k_proj<<<dim3(256, 8), 256, 0, stream>>>(mln, wcat_t, bg, qb, kb, vt, gb);
  k_attn<<<S * H, 256, 0, stream>>>(qb, kb, vt, gb, zbb, mask, ogb);
  k_out<<<dim3(256, 2), 256, 0, stream>>>(ogb, wot, bo, out);
}

// Round 10
// 129.731 us; speedup vs baseline: 2.6433x; 2.5554x over previous
//
#include <hip/hip_runtime.h>
#include <hip/hip_bf16.h>
#include <stdint.h>

#define S 128
#define R 256
#define CM 256
#define CZ 128
#define H 8
#define D 32

typedef __attribute__((ext_vector_type(8))) short short8;
typedef __attribute__((ext_vector_type(4))) float f32x4;
typedef __attribute__((ext_vector_type(16))) float f32x16;
typedef __attribute__((ext_vector_type(2))) unsigned uint2v;
typedef unsigned short u16;

#define LOG2E 1.4426950408889634f

// ---------- helpers ----------
__device__ __forceinline__ float wsum(float v) {
#pragma unroll
  for (int o = 32; o > 0; o >>= 1) v += __shfl_xor(v, o, 64);
  return v;
}
__device__ __forceinline__ u16 f2bb(float f) {
  unsigned u = __float_as_uint(f);
  return (u16)((u + 0x7fffu + ((u >> 16) & 1u)) >> 16);
}
__device__ __forceinline__ float b2f(u16 u) {
  return __uint_as_float(((unsigned)u) << 16);
}
__device__ __forceinline__ unsigned pkbf16(float a, float b) {
  __hip_bfloat162 t = __float22bfloat162_rn(make_float2(a, b));
  union { __hip_bfloat162 h; unsigned u; } cv;
  cv.h = t;
  return cv.u;
}
__device__ __forceinline__ void gl_lds16(const u16* g, u16* l) {
  __builtin_amdgcn_global_load_lds(
      (const __attribute__((address_space(1))) unsigned int*)g,
      (__attribute__((address_space(3))) unsigned int*)l, 16, 0, 0);
}

// stage a [128 rows][64 cols] bf16 tile (src row stride 256 elems) into linear LDS.
__device__ __forceinline__ void stage_tile(const u16* __restrict__ src, u16* lbase,
                                           int w, int l) {
#pragma unroll
  for (int it = 0; it < 4; it++) {
    int rbase = it * 32 + w * 8;
    int row = rbase + (l >> 3);
    int gc8 = (l & 7) ^ (row & 7);
    gl_lds16(src + (size_t)row * 256 + gc8 * 8, lbase + rbase * 64);
  }
}

// ---------- kernel 0: weights -> bf16, transposed [hd'][c]; qscale*log2e folded ----------
__global__ __launch_bounds__(256) void k_prep(const float* __restrict__ wq,
                                              const float* __restrict__ wk,
                                              const float* __restrict__ wv,
                                              const float* __restrict__ wg,
                                              const float* __restrict__ wo,
                                              u16* __restrict__ wcat_t,
                                              u16* __restrict__ wot) {
  __shared__ float t[64][65];
  int mat = blockIdx.y;  // 0..4
  const float* src = (mat == 0) ? wq : (mat == 1) ? wk : (mat == 2) ? wv
                     : (mat == 3) ? wg : wo;
  // q: 1/sqrt(D) * log2(e) folded (softmax uses exp2)
  float scale = (mat == 0) ? 0.17677669529663687f * LOG2E : 1.0f;
  u16* dst = (mat < 4) ? (wcat_t + mat * 256 * 256) : wot;
  int ti = blockIdx.x >> 2, tj = blockIdx.x & 3;
  int tid = threadIdx.x;
  int cc = tid & 63, rr4 = tid >> 6;
#pragma unroll
  for (int it = 0; it < 16; it++) {
    int ic = it * 4 + rr4;
    t[ic][cc] = src[(tj * 64 + ic) * 256 + ti * 64 + cc];
  }
  __syncthreads();
#pragma unroll
  for (int it = 0; it < 16; it++) {
    int oh = it * 4 + rr4;
    dst[(ti * 64 + oh) * 256 + tj * 64 + cc] = f2bb(t[cc][oh] * scale);
  }
}

// ---------- kernel 1: pair bias -> bf16 TRANSPOSED zbb[h][col*256+q], log2e folded ----------
__global__ __launch_bounds__(256) void k_zbias(const float* __restrict__ z,
                                               const float* __restrict__ lng,
                                               const float* __restrict__ lnb,
                                               const float* __restrict__ wz,
                                               u16* __restrict__ zbb) {
  int tid = threadIdx.x;
  int l = tid & 63, w = tid >> 6;
  int psub = l >> 3, cg = l & 7;
  int op = blockIdx.x * 32 + w * 8 + psub;   // op = q*256 + col (z pair index)
  const float* zr = z + (size_t)op * CZ;
  float4 v[4];
#pragma unroll
  for (int i = 0; i < 4; i++) v[i] = *(const float4*)(zr + i * 32 + cg * 4);
  float sum = 0.f, ssq = 0.f;
#pragma unroll
  for (int i = 0; i < 4; i++) {
    sum += v[i].x + v[i].y + v[i].z + v[i].w;
    ssq += v[i].x * v[i].x + v[i].y * v[i].y + v[i].z * v[i].z + v[i].w * v[i].w;
  }
  sum += __shfl_xor(sum, 1, 64); sum += __shfl_xor(sum, 2, 64); sum += __shfl_xor(sum, 4, 64);
  ssq += __shfl_xor(ssq, 1, 64); ssq += __shfl_xor(ssq, 2, 64); ssq += __shfl_xor(ssq, 4, 64);
  float mu = sum * (1.0f / CZ);
  float rs = rsqrtf(ssq * (1.0f / CZ) - mu * mu + 1e-5f);
  float ph[8];
#pragma unroll
  for (int hh = 0; hh < 8; hh++) ph[hh] = 0.f;
#pragma unroll
  for (int i = 0; i < 4; i++) {
    int c0 = i * 32 + cg * 4;
    float4 gg = *(const float4*)(lng + c0);
    float4 bb = *(const float4*)(lnb + c0);
    float n0 = (v[i].x - mu) * rs * gg.x + bb.x;
    float n1 = (v[i].y - mu) * rs * gg.y + bb.y;
    float n2 = (v[i].z - mu) * rs * gg.z + bb.z;
    float n3 = (v[i].w - mu) * rs * gg.w + bb.w;
#pragma unroll
    for (int jj = 0; jj < 4; jj++) {
      float nj = (jj == 0) ? n0 : (jj == 1) ? n1 : (jj == 2) ? n2 : n3;
      float4 w0 = *(const float4*)(wz + (c0 + jj) * 8);
      float4 w1 = *(const float4*)(wz + (c0 + jj) * 8 + 4);
      ph[0] = fmaf(nj, w0.x, ph[0]); ph[1] = fmaf(nj, w0.y, ph[1]);
      ph[2] = fmaf(nj, w0.z, ph[2]); ph[3] = fmaf(nj, w0.w, ph[3]);
      ph[4] = fmaf(nj, w1.x, ph[4]); ph[5] = fmaf(nj, w1.y, ph[5]);
      ph[6] = fmaf(nj, w1.z, ph[6]); ph[7] = fmaf(nj, w1.w, ph[7]);
    }
  }
  // component-splitting reduce over the 8 lanes of the pair (xor 1,2,4)
  float a[4];
#pragma unroll
  for (int j = 0; j < 4; j++) {
    float keep = (l & 1) ? ph[4 + j] : ph[j];
    float send = (l & 1) ? ph[j] : ph[4 + j];
    a[j] = keep + __shfl_xor(send, 1, 64);
  }
  float b2[2];
#pragma unroll
  for (int j = 0; j < 2; j++) {
    float keep = (l & 2) ? a[2 + j] : a[j];
    float send = (l & 2) ? a[j] : a[2 + j];
    b2[j] = keep + __shfl_xor(send, 2, 64);
  }
  float keep = (l & 4) ? b2[1] : b2[0];
  float send = (l & 4) ? b2[0] : b2[1];
  float c = keep + __shfl_xor(send, 4, 64);
  int hh = 4 * (l & 1) + (l & 2) + ((l & 4) >> 2);
  // transposed store: [h][col*256 + q]
  zbb[(size_t)hh * 65536 + (size_t)(op & 255) * 256 + (op >> 8)] = f2bb(c * LOG2E);
}

// ---------- kernel 2: LN(m) -> bf16 ----------
__global__ __launch_bounds__(256) void k_lnm(const float* __restrict__ m,
                                             const float* __restrict__ g,
                                             const float* __restrict__ b,
                                             u16* __restrict__ mln) {
  int w = threadIdx.x >> 6, lane = threadIdx.x & 63;
  size_t row = (size_t)blockIdx.x * 4 + w;
  const float4 v = *(const float4*)(m + row * 256 + lane * 4);
  float sum = wsum(v.x + v.y + v.z + v.w);
  float ssq = wsum(v.x * v.x + v.y * v.y + v.z * v.z + v.w * v.w);
  float mu = sum * (1.f / 256);
  float rs = rsqrtf(ssq * (1.f / 256) - mu * mu + 1e-5f);
  const float4 gg = *(const float4*)(g + lane * 4);
  const float4 bb = *(const float4*)(b + lane * 4);
  ushort4 o;
  o.x = f2bb((v.x - mu) * rs * gg.x + bb.x);
  o.y = f2bb((v.y - mu) * rs * gg.y + bb.y);
  o.z = f2bb((v.z - mu) * rs * gg.z + bb.z);
  o.w = f2bb((v.w - mu) * rs * gg.w + bb.w);
  *(ushort4*)(mln + row * 256 + lane * 4) = o;
}

// ---------- kernel 3: 128x128-tile MFMA GEMM  mln @ Wcat -> q/k/vfrag/g ----------
__global__ __launch_bounds__(256) void k_proj(const u16* __restrict__ mln,
                                              const u16* __restrict__ wcat_t,
                                              const float* __restrict__ bg,
                                              u16* __restrict__ qb,
                                              u16* __restrict__ kbuf,
                                              u16* __restrict__ vt,
                                              u16* __restrict__ gb) {
  __shared__ __align__(16) u16 lds[4 * 8192];  // A0 A1 B0 B1 (16KB each)
  int tid = threadIdx.x;
  int w = tid >> 6, l = tid & 63;
  int l15 = l & 15, lg = l >> 4;
  int wr = w >> 1, wc = w & 1;
  int grow0 = blockIdx.x * 128;
  int hdt0 = blockIdx.y * 128;
  const u16* asrc = mln + (size_t)grow0 * 256;
  const u16* bsrc = wcat_t + (size_t)hdt0 * 256;

  stage_tile(asrc, lds, w, l);
  stage_tile(bsrc, lds + 16384, w, l);
  __syncthreads();

  f32x4 acc[4][4];
#pragma unroll
  for (int mi = 0; mi < 4; mi++)
#pragma unroll
    for (int ni = 0; ni < 4; ni++) acc[mi][ni] = (f32x4){0.f, 0.f, 0.f, 0.f};

#pragma unroll
  for (int kt = 0; kt < 4; kt++) {
    if (kt < 3) {
      stage_tile(asrc + (kt + 1) * 64, lds + ((kt + 1) & 1) * 8192, w, l);
      stage_tile(bsrc + (kt + 1) * 64, lds + 16384 + ((kt + 1) & 1) * 8192, w, l);
    }
    const u16* Ab = lds + (kt & 1) * 8192;
    const u16* Bb = lds + 16384 + (kt & 1) * 8192;
#pragma unroll
    for (int ks = 0; ks < 2; ks++) {
      short8 af[4], bf[4];
#pragma unroll
      for (int i = 0; i < 4; i++) {
        int ra = wr * 64 + i * 16 + l15;
        af[i] = *(const short8*)(Ab + ra * 64 + (((ks * 4 + lg) ^ (ra & 7)) << 3));
        int rb = wc * 64 + i * 16 + l15;
        bf[i] = *(const short8*)(Bb + rb * 64 + (((ks * 4 + lg) ^ (rb & 7)) << 3));
      }
#pragma unroll
      for (int mi = 0; mi < 4; mi++)
#pragma unroll
        for (int ni = 0; ni < 4; ni++)
          acc[mi][ni] =
              __builtin_amdgcn_mfma_f32_16x16x32_bf16(af[mi], bf[ni], acc[mi][ni], 0, 0, 0);
    }
    __syncthreads();
  }

  // ---- epilogue: re-stage through LDS for coalesced uint4 stores ----
  int by = blockIdx.y;
  int mat = by >> 1;            // 0:q 1:k 2:v(frag layout) 3:g
  int s = grow0 >> 8, r0 = grow0 & 255;
  int hbase = (by & 1) * 128;
  u16* stg = lds;               // [128][136] bf16

  if (mat == 2) {
    // stage transposed: stg[hd_loc][k_loc]
#pragma unroll
    for (int mi = 0; mi < 4; mi++)
#pragma unroll
      for (int ni = 0; ni < 4; ni++)
#pragma unroll
        for (int j = 0; j < 4; j++) {
          int rl = wr * 64 + mi * 16 + lg * 4 + j;
          int hl = wc * 64 + ni * 16 + l15;
          stg[hl * 136 + rl] = f2bb(acc[mi][ni][j]);
        }
    __syncthreads();
    // frag layout: vt[((s*8+h)*16 + k16)*512 + l5*256 + d*8 + (k&7)]
#pragma unroll
    for (int it = 0; it < 8; it++) {
      int idx = it * 256 + tid;
      int hd_l = idx & 127, k8 = idx >> 7;      // k8: 0..15 (8-element k chunk)
      uint4 val = *(const uint4*)(stg + hd_l * 136 + k8 * 8);
      int hd = hbase + hd_l;
      int h = hd >> 5, d = hd & 31;
      int kg = r0 + k8 * 8;
      size_t off = (((size_t)(s * 8 + h) * 16 + (kg >> 4)) * 2 + ((kg >> 3) & 1)) * 256 + d * 8;
      *(uint4*)(vt + off) = val;
    }
  } else {
    float bgv[4];
    if (mat == 3) {
#pragma unroll
      for (int ni = 0; ni < 4; ni++) bgv[ni] = bg[hbase + wc * 64 + ni * 16 + l15];
    }
#pragma unroll
    for (int mi = 0; mi < 4; mi++)
#pragma unroll
      for (int ni = 0; ni < 4; ni++)
#pragma unroll
        for (int j = 0; j < 4; j++) {
          int rl = wr * 64 + mi * 16 + lg * 4 + j;
          int hl = wc * 64 + ni * 16 + l15;
          float v = acc[mi][ni][j];
          if (mat == 3) v = 1.0f / (1.0f + __expf(-(v + bgv[ni])));
          stg[rl * 136 + hl] = f2bb(v);
        }
    __syncthreads();
#pragma unroll
    for (int it = 0; it < 8; it++) {
      int idx = it * 256 + tid;
      int rl = idx >> 4, c = idx & 15;
      uint4 val = *(const uint4*)(stg + rl * 136 + c * 8);
      int hd = hbase + c * 8;
      if (mat == 3) {
        *(uint4*)(gb + (size_t)(grow0 + rl) * 256 + hd) = val;
      } else {
        u16* dst = (mat == 0) ? qb : kbuf;
        *(uint4*)(dst + ((size_t)(s * 8 + (hd >> 5)) * 256 + r0 + rl) * 32 + (hd & 31)) = val;
      }
    }
  }
}

// ---------- kernel 4: swapped-QK 32x32 MFMA flash attention, register softmax ----------
// Grid: S*H*2 blocks; each wave owns ONE 32-q-row tile (low register pressure, no spill).
__global__ __launch_bounds__(256) void k_attn(const u16* __restrict__ qb,
                                              const u16* __restrict__ kbuf,
                                              const u16* __restrict__ vt,
                                              const u16* __restrict__ gb,
                                              const u16* __restrict__ zbb,
                                              const float* __restrict__ mask,
                                              u16* __restrict__ og) {
  int blk = blockIdx.x;                 // s*16 + h*2 + half
  int s = blk >> 4, h = (blk >> 1) & 7, half = blk & 1;
  int tid = threadIdx.x, w = tid >> 6, l = tid & 63;
  int l31 = l & 31, l5 = l >> 5;
  int q0 = half * 128 + w * 32;
  size_t base = (size_t)(s * 8 + h) * 256 * 32;
  const u16* zcol = zbb + (size_t)h * 65536;   // [col][q] bf16, log2e folded
  const float* mrow = mask + s * 256;

  // Q B-frags: Q[q0+l31][dh*16 + l5*8 ..+7]
  short8 qf[2];
#pragma unroll
  for (int dh = 0; dh < 2; dh++)
    qf[dh] = *(const short8*)(qb + base + (size_t)(q0 + l31) * 32 + dh * 16 + l5 * 8);

  f32x16 oacc;
#pragma unroll
  for (int j = 0; j < 16; j++) oacc[j] = 0.f;
  float ls0 = 0.f, ls1 = 0.f;

#pragma unroll
  for (int kb = 0; kb < 4; kb++) {
    int kbase = kb * 64;
    // K A-frags: K[kbase+kt*32+l31][dh*16 + l5*8..]
    short8 kf[2][2];
#pragma unroll
    for (int kt = 0; kt < 2; kt++)
#pragma unroll
      for (int dh = 0; dh < 2; dh++)
        kf[kt][dh] = *(const short8*)(kbuf + base + (size_t)(kbase + kt * 32 + l31) * 32 +
                                      dh * 16 + l5 * 8);
    // V B-frags from frag layout: fully coalesced (16B/lane)
    short8 vf[2][2];
#pragma unroll
    for (int kt = 0; kt < 2; kt++)
#pragma unroll
      for (int ks = 0; ks < 2; ks++)
        vf[kt][ks] = *(const short8*)(vt + ((size_t)(s * 8 + h) * 16 +
                                            (kb * 4 + kt * 2 + ks)) * 512 +
                                      l5 * 256 + l31 * 8);

#pragma unroll
    for (int kt = 0; kt < 2; kt++) {
      // ---- C-init = z^T[col][q] + maskbias; reg j of cc: col = kt*32+cc*8+l5*4+j
      f32x16 c;
#pragma unroll
      for (int cc = 0; cc < 4; cc++) {
        int col0 = kbase + kt * 32 + cc * 8 + l5 * 4;
        const u16* zp = zcol + (size_t)col0 * 256 + q0 + l31;
        float4 mv = *(const float4*)(mrow + col0);
        c[4 * cc + 0] = b2f(zp[0])   + (LOG2E * 1e9f) * (mv.x - 1.0f);
        c[4 * cc + 1] = b2f(zp[256]) + (LOG2E * 1e9f) * (mv.y - 1.0f);
        c[4 * cc + 2] = b2f(zp[512]) + (LOG2E * 1e9f) * (mv.z - 1.0f);
        c[4 * cc + 3] = b2f(zp[768]) + (LOG2E * 1e9f) * (mv.w - 1.0f);
      }
      // ---- S^T = K @ Q^T + C  (lane: col=q, rows=k)
      c = __builtin_amdgcn_mfma_f32_32x32x16_bf16(kf[kt][0], qf[0], c, 0, 0, 0);
      c = __builtin_amdgcn_mfma_f32_32x32x16_bf16(kf[kt][1], qf[1], c, 0, 0, 0);
      // ---- p = exp2(c); row-sum partials
      float p[16];
#pragma unroll
      for (int j = 0; j < 16; j++) {
        p[j] = __builtin_amdgcn_exp2f(c[j]);
        if (j & 1) ls1 += p[j]; else ls0 += p[j];
      }
      // ---- pack to bf16 words (compiler-managed cvt_pk + permlane)
      unsigned wd[8];
#pragma unroll
      for (int r = 0; r < 8; r++) wd[r] = pkbf16(p[2 * r], p[2 * r + 1]);
      {
        uint2v r0 = __builtin_amdgcn_permlane32_swap(wd[0], wd[2], false, false);
        wd[0] = r0[0]; wd[2] = r0[1];
        uint2v r1 = __builtin_amdgcn_permlane32_swap(wd[1], wd[3], false, false);
        wd[1] = r1[0]; wd[3] = r1[1];
        uint2v r2 = __builtin_amdgcn_permlane32_swap(wd[4], wd[6], false, false);
        wd[4] = r2[0]; wd[6] = r2[1];
        uint2v r3 = __builtin_amdgcn_permlane32_swap(wd[5], wd[7], false, false);
        wd[5] = r3[0]; wd[7] = r3[1];
      }
      union { unsigned u[4]; short8 s8; } pa0, pa1;
      pa0.u[0] = wd[0]; pa0.u[1] = wd[1]; pa0.u[2] = wd[2]; pa0.u[3] = wd[3];
      pa1.u[0] = wd[4]; pa1.u[1] = wd[5]; pa1.u[2] = wd[6]; pa1.u[3] = wd[7];
      // ---- O[q][d] += P @ V
      oacc = __builtin_amdgcn_mfma_f32_32x32x16_bf16(pa0.s8, vf[kt][0], oacc, 0, 0, 0);
      oacc = __builtin_amdgcn_mfma_f32_32x32x16_bf16(pa1.s8, vf[kt][1], oacc, 0, 0, 0);
    }
  }
  // ---- finalize row sums (lane holds q=l31; halves hold disjoint k-sets)
  float lv = ls0 + ls1;
  lv += __shfl_xor(lv, 32, 64);
  float inv = 1.0f / lv;
  // ---- normalize, gate, store (O layout: col=l31=d, row q = (j&3)+8*(j>>2)+4*l5)
#pragma unroll
  for (int j = 0; j < 16; j++) {
    int qrow = (j & 3) + 8 * (j >> 2) + 4 * l5;
    float invj = __shfl(inv, qrow, 64);
    int q = q0 + qrow;
    size_t ob = ((size_t)s * 256 + q) * 256 + h * 32 + l31;
    float gv = b2f(gb[ob]);
    og[ob] = f2bb(oacc[j] * invj * gv);
  }
}

// ---------- kernel 5: 128x128-tile MFMA GEMM  og @ WO + bo -> out f32 ----------
__global__ __launch_bounds__(256) void k_out(const u16* __restrict__ og,
                                             const u16* __restrict__ wot,
                                             const float* __restrict__ bo,
                                             float* __restrict__ out) {
  __shared__ __align__(16) u16 lds[4 * 8192];
  int tid = threadIdx.x;
  int w = tid >> 6, l = tid & 63;
  int l15 = l & 15, lg = l >> 4;
  int wr = w >> 1, wc = w & 1;
  int grow0 = blockIdx.x * 128;
  int ct0 = blockIdx.y * 128;
  const u16* asrc = og + (size_t)grow0 * 256;
  const u16* bsrc = wot + (size_t)ct0 * 256;

  stage_tile(asrc, lds, w, l);
  stage_tile(bsrc, lds + 16384, w, l);
  __syncthreads();

  f32x4 acc[4][4];
#pragma unroll
  for (int mi = 0; mi < 4; mi++)
#pragma unroll
    for (int ni = 0; ni < 4; ni++) acc[mi][ni] = (f32x4){0.f, 0.f, 0.f, 0.f};

#pragma unroll
  for (int kt = 0; kt < 4; kt++) {
    if (kt < 3) {
      stage_tile(asrc + (kt + 1) * 64, lds + ((kt + 1) & 1) * 8192, w, l);
      stage_tile(bsrc + (kt + 1) * 64, lds + 16384 + ((kt + 1) & 1) * 8192, w, l);
    }
    const u16* Ab = lds + (kt & 1) * 8192;
    const u16* Bb = lds + 16384 + (kt & 1) * 8192;
#pragma unroll
    for (int ks = 0; ks < 2; ks++) {
      short8 af[4], bf[4];
#pragma unroll
      for (int i = 0; i < 4; i++) {
        int ra = wr * 64 + i * 16 + l15;
        af[i] = *(const short8*)(Ab + ra * 64 + (((ks * 4 + lg) ^ (ra & 7)) << 3));
        int rb = wc * 64 + i * 16 + l15;
        bf[i] = *(const short8*)(Bb + rb * 64 + (((ks * 4 + lg) ^ (rb & 7)) << 3));
      }
#pragma unroll
      for (int mi = 0; mi < 4; mi++)
#pragma unroll
        for (int ni = 0; ni < 4; ni++)
          acc[mi][ni] =
              __builtin_amdgcn_mfma_f32_16x16x32_bf16(af[mi], bf[ni], acc[mi][ni], 0, 0, 0);
    }
    __syncthreads();
  }

  int cout_base = ct0 + wc * 64;
#pragma unroll
  for (int ni = 0; ni < 4; ni++) {
    int cout = cout_base + ni * 16 + l15;
    float bov = bo[cout];
#pragma unroll
    for (int mi = 0; mi < 4; mi++)
#pragma unroll
      for (int j = 0; j < 4; j++)
        out[(size_t)(grow0 + wr * 64 + mi * 16 + lg * 4 + j) * 256 + cout] =
            acc[mi][ni][j] + bov;
  }
}

extern "C" void kernel_launch(void* const* d_in, const int* in_sizes, int n_in,
                              void* d_out, int out_size, void* d_ws, size_t ws_size,
                              hipStream_t stream) {
  const float* m      = (const float*)d_in[0];
  const float* z      = (const float*)d_in[1];
  const float* mask   = (const float*)d_in[2];
  const float* ln_m_g = (const float*)d_in[3];
  const float* ln_m_b = (const float*)d_in[4];
  const float* ln_z_g = (const float*)d_in[5];
  const float* ln_z_b = (const float*)d_in[6];
  const float* wz     = (const float*)d_in[7];
  const float* wq     = (const float*)d_in[8];
  const float* wk     = (const float*)d_in[9];
  const float* wv     = (const float*)d_in[10];
  const float* wg     = (const float*)d_in[11];
  const float* bg     = (const float*)d_in[12];
  const float* wo     = (const float*)d_in[13];
  const float* bo     = (const float*)d_in[14];
  float* out = (float*)d_out;

  char* ws = (char*)d_ws;
  const size_t MiB = 1u << 20;
  u16* zbb     = (u16*)(ws);                        // 1 MiB  [h][col*256+q] bf16
  u16* wcat_t  = (u16*)(ws + 2 * MiB);              // 512 KiB
  u16* wot     = (u16*)(ws + 2 * MiB + 512 * 1024); // 128 KiB
  u16* mln     = (u16*)(ws + 3 * MiB);              // 16 MiB
  u16* qb      = (u16*)(ws + 19 * MiB);             // 16 MiB  [s][h][r][d]
  u16* kb      = (u16*)(ws + 35 * MiB);             // 16 MiB  [s][h][r][d]
  u16* vt      = (u16*)(ws + 51 * MiB);             // 16 MiB  V frag layout
  u16* gb      = (u16*)(ws + 67 * MiB);             // 16 MiB  [row][hd]
  u16* ogb     = (u16*)(ws + 83 * MiB);             // 16 MiB  [row][hd]
  (void)in_sizes; (void)n_in; (void)out_size; (void)ws_size;

  k_prep<<<dim3(16, 5), 256, 0, stream>>>(wq, wk, wv, wg, wo, wcat_t, wot);
  k_zbias<<<(R * R) / 32, 256, 0, stream>>>(z, ln_z_g, ln_z_b, wz, zbb);
  k_lnm<<<(S * R) / 4, 256, 0, stream>>>(m, ln_m_g, ln_m_b, mln);
  k_proj<<<dim3(256, 8), 256, 0, stream>>>(mln, wcat_t, bg, qb, kb, vt, gb);
  k_attn<<<S * H * 2, 256, 0, stream>>>(qb, kb, vt, gb, zbb, mask, ogb);
  k_out<<<dim3(256, 2), 256, 0, stream>>>(ogb, wot, bo, out);
}

// Round 11
// 124.694 us; speedup vs baseline: 2.7501x; 1.0404x over previous
//
#include <hip/hip_runtime.h>
#include <hip/hip_bf16.h>
#include <stdint.h>

#define S 128
#define R 256
#define CM 256
#define CZ 128
#define H 8
#define D 32

typedef __attribute__((ext_vector_type(8))) short short8;
typedef __attribute__((ext_vector_type(4))) float f32x4;
typedef __attribute__((ext_vector_type(16))) float f32x16;
typedef __attribute__((ext_vector_type(2))) unsigned uint2v;
typedef unsigned short u16;

#define LOG2E 1.4426950408889634f

// ---------- helpers ----------
__device__ __forceinline__ float wsum(float v) {
#pragma unroll
  for (int o = 32; o > 0; o >>= 1) v += __shfl_xor(v, o, 64);
  return v;
}
__device__ __forceinline__ u16 f2bb(float f) {
  unsigned u = __float_as_uint(f);
  return (u16)((u + 0x7fffu + ((u >> 16) & 1u)) >> 16);
}
__device__ __forceinline__ float b2f(u16 u) {
  return __uint_as_float(((unsigned)u) << 16);
}
__device__ __forceinline__ unsigned pkbf16(float a, float b) {
  __hip_bfloat162 t = __float22bfloat162_rn(make_float2(a, b));
  union { __hip_bfloat162 h; unsigned u; } cv;
  cv.h = t;
  return cv.u;
}
__device__ __forceinline__ void gl_lds16(const u16* g, u16* l) {
  __builtin_amdgcn_global_load_lds(
      (const __attribute__((address_space(1))) unsigned int*)g,
      (__attribute__((address_space(3))) unsigned int*)l, 16, 0, 0);
}

// stage a [128 rows][64 cols] bf16 tile (src row stride 256 elems) into linear LDS.
__device__ __forceinline__ void stage_tile(const u16* __restrict__ src, u16* lbase,
                                           int w, int l) {
#pragma unroll
  for (int it = 0; it < 4; it++) {
    int rbase = it * 32 + w * 8;
    int row = rbase + (l >> 3);
    int gc8 = (l & 7) ^ (row & 7);
    gl_lds16(src + (size_t)row * 256 + gc8 * 8, lbase + rbase * 64);
  }
}

// ---------- kernel 0: weights -> bf16, transposed [hd'][c]; qscale*log2e folded ----------
__global__ __launch_bounds__(256) void k_prep(const float* __restrict__ wq,
                                              const float* __restrict__ wk,
                                              const float* __restrict__ wv,
                                              const float* __restrict__ wg,
                                              const float* __restrict__ wo,
                                              u16* __restrict__ wcat_t,
                                              u16* __restrict__ wot) {
  __shared__ float t[64][65];
  int mat = blockIdx.y;  // 0..4
  const float* src = (mat == 0) ? wq : (mat == 1) ? wk : (mat == 2) ? wv
                     : (mat == 3) ? wg : wo;
  // q: 1/sqrt(D) * log2(e) folded (softmax uses exp2)
  float scale = (mat == 0) ? 0.17677669529663687f * LOG2E : 1.0f;
  u16* dst = (mat < 4) ? (wcat_t + mat * 256 * 256) : wot;
  int ti = blockIdx.x >> 2, tj = blockIdx.x & 3;
  int tid = threadIdx.x;
  int cc = tid & 63, rr4 = tid >> 6;
#pragma unroll
  for (int it = 0; it < 16; it++) {
    int ic = it * 4 + rr4;
    t[ic][cc] = src[(tj * 64 + ic) * 256 + ti * 64 + cc];
  }
  __syncthreads();
#pragma unroll
  for (int it = 0; it < 16; it++) {
    int oh = it * 4 + rr4;
    dst[(ti * 64 + oh) * 256 + tj * 64 + cc] = f2bb(t[cc][oh] * scale);
  }
}

// ---------- kernel 1: pair bias -> bf16 zbb[h][col>>2][q][col&3], log2e folded ----------
// Interleaved layout: lane in k_attn loads one ushort4 = 4 consecutive cols for its q.
__global__ __launch_bounds__(256) void k_zbias(const float* __restrict__ z,
                                               const float* __restrict__ lng,
                                               const float* __restrict__ lnb,
                                               const float* __restrict__ wz,
                                               u16* __restrict__ zbb) {
  int tid = threadIdx.x;
  int l = tid & 63, w = tid >> 6;
  int psub = l >> 3, cg = l & 7;
  int op = blockIdx.x * 32 + w * 8 + psub;   // op = q*256 + col (z pair index)
  const float* zr = z + (size_t)op * CZ;
  float4 v[4];
#pragma unroll
  for (int i = 0; i < 4; i++) v[i] = *(const float4*)(zr + i * 32 + cg * 4);
  float sum = 0.f, ssq = 0.f;
#pragma unroll
  for (int i = 0; i < 4; i++) {
    sum += v[i].x + v[i].y + v[i].z + v[i].w;
    ssq += v[i].x * v[i].x + v[i].y * v[i].y + v[i].z * v[i].z + v[i].w * v[i].w;
  }
  sum += __shfl_xor(sum, 1, 64); sum += __shfl_xor(sum, 2, 64); sum += __shfl_xor(sum, 4, 64);
  ssq += __shfl_xor(ssq, 1, 64); ssq += __shfl_xor(ssq, 2, 64); ssq += __shfl_xor(ssq, 4, 64);
  float mu = sum * (1.0f / CZ);
  float rs = rsqrtf(ssq * (1.0f / CZ) - mu * mu + 1e-5f);
  float ph[8];
#pragma unroll
  for (int hh = 0; hh < 8; hh++) ph[hh] = 0.f;
#pragma unroll
  for (int i = 0; i < 4; i++) {
    int c0 = i * 32 + cg * 4;
    float4 gg = *(const float4*)(lng + c0);
    float4 bb = *(const float4*)(lnb + c0);
    float n0 = (v[i].x - mu) * rs * gg.x + bb.x;
    float n1 = (v[i].y - mu) * rs * gg.y + bb.y;
    float n2 = (v[i].z - mu) * rs * gg.z + bb.z;
    float n3 = (v[i].w - mu) * rs * gg.w + bb.w;
#pragma unroll
    for (int jj = 0; jj < 4; jj++) {
      float nj = (jj == 0) ? n0 : (jj == 1) ? n1 : (jj == 2) ? n2 : n3;
      float4 w0 = *(const float4*)(wz + (c0 + jj) * 8);
      float4 w1 = *(const float4*)(wz + (c0 + jj) * 8 + 4);
      ph[0] = fmaf(nj, w0.x, ph[0]); ph[1] = fmaf(nj, w0.y, ph[1]);
      ph[2] = fmaf(nj, w0.z, ph[2]); ph[3] = fmaf(nj, w0.w, ph[3]);
      ph[4] = fmaf(nj, w1.x, ph[4]); ph[5] = fmaf(nj, w1.y, ph[5]);
      ph[6] = fmaf(nj, w1.z, ph[6]); ph[7] = fmaf(nj, w1.w, ph[7]);
    }
  }
  // component-splitting reduce over the 8 lanes of the pair (xor 1,2,4)
  float a[4];
#pragma unroll
  for (int j = 0; j < 4; j++) {
    float keep = (l & 1) ? ph[4 + j] : ph[j];
    float send = (l & 1) ? ph[j] : ph[4 + j];
    a[j] = keep + __shfl_xor(send, 1, 64);
  }
  float b2[2];
#pragma unroll
  for (int j = 0; j < 2; j++) {
    float keep = (l & 2) ? a[2 + j] : a[j];
    float send = (l & 2) ? a[j] : a[2 + j];
    b2[j] = keep + __shfl_xor(send, 2, 64);
  }
  float keep = (l & 4) ? b2[1] : b2[0];
  float send = (l & 4) ? b2[0] : b2[1];
  float c = keep + __shfl_xor(send, 4, 64);
  int hh = 4 * (l & 1) + (l & 2) + ((l & 4) >> 2);
  int q = op >> 8, col = op & 255;
  // interleaved store: [h][col>>2][q][col&3]
  zbb[(size_t)hh * 65536 + (size_t)(col >> 2) * 1024 + q * 4 + (col & 3)] = f2bb(c * LOG2E);
}

// ---------- kernel 2: LN(m) -> bf16 ----------
__global__ __launch_bounds__(256) void k_lnm(const float* __restrict__ m,
                                             const float* __restrict__ g,
                                             const float* __restrict__ b,
                                             u16* __restrict__ mln) {
  int w = threadIdx.x >> 6, lane = threadIdx.x & 63;
  size_t row = (size_t)blockIdx.x * 4 + w;
  const float4 v = *(const float4*)(m + row * 256 + lane * 4);
  float sum = wsum(v.x + v.y + v.z + v.w);
  float ssq = wsum(v.x * v.x + v.y * v.y + v.z * v.z + v.w * v.w);
  float mu = sum * (1.f / 256);
  float rs = rsqrtf(ssq * (1.f / 256) - mu * mu + 1e-5f);
  const float4 gg = *(const float4*)(g + lane * 4);
  const float4 bb = *(const float4*)(b + lane * 4);
  ushort4 o;
  o.x = f2bb((v.x - mu) * rs * gg.x + bb.x);
  o.y = f2bb((v.y - mu) * rs * gg.y + bb.y);
  o.z = f2bb((v.z - mu) * rs * gg.z + bb.z);
  o.w = f2bb((v.w - mu) * rs * gg.w + bb.w);
  *(ushort4*)(mln + row * 256 + lane * 4) = o;
}

// ---------- kernel 3: 128x128-tile MFMA GEMM  mln @ Wcat -> q/k/vfrag/g ----------
__global__ __launch_bounds__(256) void k_proj(const u16* __restrict__ mln,
                                              const u16* __restrict__ wcat_t,
                                              const float* __restrict__ bg,
                                              u16* __restrict__ qb,
                                              u16* __restrict__ kbuf,
                                              u16* __restrict__ vt,
                                              u16* __restrict__ gb) {
  __shared__ __align__(16) u16 lds[4 * 8192];  // A0 A1 B0 B1 (16KB each)
  int tid = threadIdx.x;
  int w = tid >> 6, l = tid & 63;
  int l15 = l & 15, lg = l >> 4;
  int wr = w >> 1, wc = w & 1;
  int grow0 = blockIdx.x * 128;
  int hdt0 = blockIdx.y * 128;
  const u16* asrc = mln + (size_t)grow0 * 256;
  const u16* bsrc = wcat_t + (size_t)hdt0 * 256;

  stage_tile(asrc, lds, w, l);
  stage_tile(bsrc, lds + 16384, w, l);
  __syncthreads();

  f32x4 acc[4][4];
#pragma unroll
  for (int mi = 0; mi < 4; mi++)
#pragma unroll
    for (int ni = 0; ni < 4; ni++) acc[mi][ni] = (f32x4){0.f, 0.f, 0.f, 0.f};

#pragma unroll
  for (int kt = 0; kt < 4; kt++) {
    if (kt < 3) {
      stage_tile(asrc + (kt + 1) * 64, lds + ((kt + 1) & 1) * 8192, w, l);
      stage_tile(bsrc + (kt + 1) * 64, lds + 16384 + ((kt + 1) & 1) * 8192, w, l);
    }
    const u16* Ab = lds + (kt & 1) * 8192;
    const u16* Bb = lds + 16384 + (kt & 1) * 8192;
#pragma unroll
    for (int ks = 0; ks < 2; ks++) {
      short8 af[4], bf[4];
#pragma unroll
      for (int i = 0; i < 4; i++) {
        int ra = wr * 64 + i * 16 + l15;
        af[i] = *(const short8*)(Ab + ra * 64 + (((ks * 4 + lg) ^ (ra & 7)) << 3));
        int rb = wc * 64 + i * 16 + l15;
        bf[i] = *(const short8*)(Bb + rb * 64 + (((ks * 4 + lg) ^ (rb & 7)) << 3));
      }
#pragma unroll
      for (int mi = 0; mi < 4; mi++)
#pragma unroll
        for (int ni = 0; ni < 4; ni++)
          acc[mi][ni] =
              __builtin_amdgcn_mfma_f32_16x16x32_bf16(af[mi], bf[ni], acc[mi][ni], 0, 0, 0);
    }
    __syncthreads();
  }

  // ---- epilogue: re-stage through LDS for coalesced uint4 stores ----
  int by = blockIdx.y;
  int mat = by >> 1;            // 0:q 1:k 2:v(frag layout) 3:g
  int s = grow0 >> 8, r0 = grow0 & 255;
  int hbase = (by & 1) * 128;
  u16* stg = lds;               // [128][136] bf16

  if (mat == 2) {
    // stage transposed: stg[hd_loc][k_loc]
#pragma unroll
    for (int mi = 0; mi < 4; mi++)
#pragma unroll
      for (int ni = 0; ni < 4; ni++)
#pragma unroll
        for (int j = 0; j < 4; j++) {
          int rl = wr * 64 + mi * 16 + lg * 4 + j;
          int hl = wc * 64 + ni * 16 + l15;
          stg[hl * 136 + rl] = f2bb(acc[mi][ni][j]);
        }
    __syncthreads();
    // frag layout: vt[((s*8+h)*16 + k16)*512 + l5*256 + d*8 + (k&7)]
#pragma unroll
    for (int it = 0; it < 8; it++) {
      int idx = it * 256 + tid;
      int hd_l = idx & 127, k8 = idx >> 7;      // k8: 0..15 (8-element k chunk)
      uint4 val = *(const uint4*)(stg + hd_l * 136 + k8 * 8);
      int hd = hbase + hd_l;
      int h = hd >> 5, d = hd & 31;
      int kg = r0 + k8 * 8;
      size_t off = (((size_t)(s * 8 + h) * 16 + (kg >> 4)) * 2 + ((kg >> 3) & 1)) * 256 + d * 8;
      *(uint4*)(vt + off) = val;
    }
  } else {
    float bgv[4];
    if (mat == 3) {
#pragma unroll
      for (int ni = 0; ni < 4; ni++) bgv[ni] = bg[hbase + wc * 64 + ni * 16 + l15];
    }
#pragma unroll
    for (int mi = 0; mi < 4; mi++)
#pragma unroll
      for (int ni = 0; ni < 4; ni++)
#pragma unroll
        for (int j = 0; j < 4; j++) {
          int rl = wr * 64 + mi * 16 + lg * 4 + j;
          int hl = wc * 64 + ni * 16 + l15;
          float v = acc[mi][ni][j];
          if (mat == 3) v = 1.0f / (1.0f + __expf(-(v + bgv[ni])));
          stg[rl * 136 + hl] = f2bb(v);
        }
    __syncthreads();
#pragma unroll
    for (int it = 0; it < 8; it++) {
      int idx = it * 256 + tid;
      int rl = idx >> 4, c = idx & 15;
      uint4 val = *(const uint4*)(stg + rl * 136 + c * 8);
      int hd = hbase + c * 8;
      if (mat == 3) {
        *(uint4*)(gb + (size_t)(grow0 + rl) * 256 + hd) = val;
      } else {
        u16* dst = (mat == 0) ? qb : kbuf;
        *(uint4*)(dst + ((size_t)(s * 8 + (hd >> 5)) * 256 + r0 + rl) * 32 + (hd & 31)) = val;
      }
    }
  }
}

// ---------- kernel 4: swapped-QK 32x32 MFMA flash attention, register softmax ----------
// Grid: S*H*2 blocks; each wave owns ONE 32-q-row tile (low register pressure, no spill).
__global__ __launch_bounds__(256) void k_attn(const u16* __restrict__ qb,
                                              const u16* __restrict__ kbuf,
                                              const u16* __restrict__ vt,
                                              const u16* __restrict__ gb,
                                              const u16* __restrict__ zbb,
                                              const float* __restrict__ mask,
                                              u16* __restrict__ og) {
  __shared__ float mbl[256];            // mask bias, log2e folded
  int blk = blockIdx.x;                 // s*16 + h*2 + half
  int s = blk >> 4, h = (blk >> 1) & 7, half = blk & 1;
  int tid = threadIdx.x, w = tid >> 6, l = tid & 63;
  int l31 = l & 31, l5 = l >> 5;
  int q0 = half * 128 + w * 32;
  size_t base = (size_t)(s * 8 + h) * 256 * 32;
  const u16* zb4 = zbb + (size_t)h * 65536;   // [col>>2][q][col&3] bf16, log2e folded

  mbl[tid] = (LOG2E * 1e9f) * (mask[s * 256 + tid] - 1.0f);

  // Q B-frags: Q[q0+l31][dh*16 + l5*8 ..+7]
  short8 qf[2];
#pragma unroll
  for (int dh = 0; dh < 2; dh++)
    qf[dh] = *(const short8*)(qb + base + (size_t)(q0 + l31) * 32 + dh * 16 + l5 * 8);

  f32x16 oacc;
#pragma unroll
  for (int j = 0; j < 16; j++) oacc[j] = 0.f;
  float ls0 = 0.f, ls1 = 0.f;
  __syncthreads();

#pragma unroll
  for (int kb = 0; kb < 4; kb++) {
    int kbase = kb * 64;
    // K A-frags: K[kbase+kt*32+l31][dh*16 + l5*8..]
    short8 kf[2][2];
#pragma unroll
    for (int kt = 0; kt < 2; kt++)
#pragma unroll
      for (int dh = 0; dh < 2; dh++)
        kf[kt][dh] = *(const short8*)(kbuf + base + (size_t)(kbase + kt * 32 + l31) * 32 +
                                      dh * 16 + l5 * 8);
    // V B-frags from frag layout: fully coalesced (16B/lane)
    short8 vf[2][2];
#pragma unroll
    for (int kt = 0; kt < 2; kt++)
#pragma unroll
      for (int ks = 0; ks < 2; ks++)
        vf[kt][ks] = *(const short8*)(vt + ((size_t)(s * 8 + h) * 16 +
                                            (kb * 4 + kt * 2 + ks)) * 512 +
                                      l5 * 256 + l31 * 8);

#pragma unroll
    for (int kt = 0; kt < 2; kt++) {
      // ---- C-init: vectorized z (ushort4 = 4 cols) + LDS mask bias
      f32x16 c;
#pragma unroll
      for (int cc = 0; cc < 4; cc++) {
        int col0 = kbase + kt * 32 + cc * 8 + l5 * 4;
        ushort4 zu = *(const ushort4*)(zb4 + ((size_t)(col0 >> 2) << 10) + ((q0 + l31) << 2));
        float4 mv = *(const float4*)(mbl + col0);
        c[4 * cc + 0] = b2f(zu.x) + mv.x;
        c[4 * cc + 1] = b2f(zu.y) + mv.y;
        c[4 * cc + 2] = b2f(zu.z) + mv.z;
        c[4 * cc + 3] = b2f(zu.w) + mv.w;
      }
      // ---- S^T = K @ Q^T + C  (lane: col=q, rows=k)
      c = __builtin_amdgcn_mfma_f32_32x32x16_bf16(kf[kt][0], qf[0], c, 0, 0, 0);
      c = __builtin_amdgcn_mfma_f32_32x32x16_bf16(kf[kt][1], qf[1], c, 0, 0, 0);
      // ---- p = exp2(c); row-sum partials
      float p[16];
#pragma unroll
      for (int j = 0; j < 16; j++) {
        p[j] = __builtin_amdgcn_exp2f(c[j]);
        if (j & 1) ls1 += p[j]; else ls0 += p[j];
      }
      // ---- pack to bf16 words (compiler-managed cvt_pk + permlane)
      unsigned wd[8];
#pragma unroll
      for (int r = 0; r < 8; r++) wd[r] = pkbf16(p[2 * r], p[2 * r + 1]);
      {
        uint2v r0 = __builtin_amdgcn_permlane32_swap(wd[0], wd[2], false, false);
        wd[0] = r0[0]; wd[2] = r0[1];
        uint2v r1 = __builtin_amdgcn_permlane32_swap(wd[1], wd[3], false, false);
        wd[1] = r1[0]; wd[3] = r1[1];
        uint2v r2 = __builtin_amdgcn_permlane32_swap(wd[4], wd[6], false, false);
        wd[4] = r2[0]; wd[6] = r2[1];
        uint2v r3 = __builtin_amdgcn_permlane32_swap(wd[5], wd[7], false, false);
        wd[5] = r3[0]; wd[7] = r3[1];
      }
      union { unsigned u[4]; short8 s8; } pa0, pa1;
      pa0.u[0] = wd[0]; pa0.u[1] = wd[1]; pa0.u[2] = wd[2]; pa0.u[3] = wd[3];
      pa1.u[0] = wd[4]; pa1.u[1] = wd[5]; pa1.u[2] = wd[6]; pa1.u[3] = wd[7];
      // ---- O[q][d] += P @ V
      oacc = __builtin_amdgcn_mfma_f32_32x32x16_bf16(pa0.s8, vf[kt][0], oacc, 0, 0, 0);
      oacc = __builtin_amdgcn_mfma_f32_32x32x16_bf16(pa1.s8, vf[kt][1], oacc, 0, 0, 0);
    }
  }
  // ---- finalize row sums (lane holds q=l31; halves hold disjoint k-sets)
  float lv = ls0 + ls1;
  lv += __shfl_xor(lv, 32, 64);
  float inv = 1.0f / lv;
  // ---- normalize, gate, store (O layout: col=l31=d, row q = (j&3)+8*(j>>2)+4*l5)
#pragma unroll
  for (int j = 0; j < 16; j++) {
    int qrow = (j & 3) + 8 * (j >> 2) + 4 * l5;
    float invj = __shfl(inv, qrow, 64);
    int q = q0 + qrow;
    size_t ob = ((size_t)s * 256 + q) * 256 + h * 32 + l31;
    float gv = b2f(gb[ob]);
    og[ob] = f2bb(oacc[j] * invj * gv);
  }
}

// ---------- kernel 5: 128x128-tile MFMA GEMM  og @ WO + bo -> out f32 ----------
__global__ __launch_bounds__(256) void k_out(const u16* __restrict__ og,
                                             const u16* __restrict__ wot,
                                             const float* __restrict__ bo,
                                             float* __restrict__ out) {
  __shared__ __align__(16) u16 lds[4 * 8192];
  int tid = threadIdx.x;
  int w = tid >> 6, l = tid & 63;
  int l15 = l & 15, lg = l >> 4;
  int wr = w >> 1, wc = w & 1;
  int grow0 = blockIdx.x * 128;
  int ct0 = blockIdx.y * 128;
  const u16* asrc = og + (size_t)grow0 * 256;
  const u16* bsrc = wot + (size_t)ct0 * 256;

  stage_tile(asrc, lds, w, l);
  stage_tile(bsrc, lds + 16384, w, l);
  __syncthreads();

  f32x4 acc[4][4];
#pragma unroll
  for (int mi = 0; mi < 4; mi++)
#pragma unroll
    for (int ni = 0; ni < 4; ni++) acc[mi][ni] = (f32x4){0.f, 0.f, 0.f, 0.f};

#pragma unroll
  for (int kt = 0; kt < 4; kt++) {
    if (kt < 3) {
      stage_tile(asrc + (kt + 1) * 64, lds + ((kt + 1) & 1) * 8192, w, l);
      stage_tile(bsrc + (kt + 1) * 64, lds + 16384 + ((kt + 1) & 1) * 8192, w, l);
    }
    const u16* Ab = lds + (kt & 1) * 8192;
    const u16* Bb = lds + 16384 + (kt & 1) * 8192;
#pragma unroll
    for (int ks = 0; ks < 2; ks++) {
      short8 af[4], bf[4];
#pragma unroll
      for (int i = 0; i < 4; i++) {
        int ra = wr * 64 + i * 16 + l15;
        af[i] = *(const short8*)(Ab + ra * 64 + (((ks * 4 + lg) ^ (ra & 7)) << 3));
        int rb = wc * 64 + i * 16 + l15;
        bf[i] = *(const short8*)(Bb + rb * 64 + (((ks * 4 + lg) ^ (rb & 7)) << 3));
      }
#pragma unroll
      for (int mi = 0; mi < 4; mi++)
#pragma unroll
        for (int ni = 0; ni < 4; ni++)
          acc[mi][ni] =
              __builtin_amdgcn_mfma_f32_16x16x32_bf16(af[mi], bf[ni], acc[mi][ni], 0, 0, 0);
    }
    __syncthreads();
  }

  int cout_base = ct0 + wc * 64;
#pragma unroll
  for (int ni = 0; ni < 4; ni++) {
    int cout = cout_base + ni * 16 + l15;
    float bov = bo[cout];
#pragma unroll
    for (int mi = 0; mi < 4; mi++)
#pragma unroll
      for (int j = 0; j < 4; j++)
        out[(size_t)(grow0 + wr * 64 + mi * 16 + lg * 4 + j) * 256 + cout] =
            acc[mi][ni][j] + bov;
  }
}

extern "C" void kernel_launch(void* const* d_in, const int* in_sizes, int n_in,
                              void* d_out, int out_size, void* d_ws, size_t ws_size,
                              hipStream_t stream) {
  const float* m      = (const float*)d_in[0];
  const float* z      = (const float*)d_in[1];
  const float* mask   = (const float*)d_in[2];
  const float* ln_m_g = (const float*)d_in[3];
  const float* ln_m_b = (const float*)d_in[4];
  const float* ln_z_g = (const float*)d_in[5];
  const float* ln_z_b = (const float*)d_in[6];
  const float* wz     = (const float*)d_in[7];
  const float* wq     = (const float*)d_in[8];
  const float* wk     = (const float*)d_in[9];
  const float* wv     = (const float*)d_in[10];
  const float* wg     = (const float*)d_in[11];
  const float* bg     = (const float*)d_in[12];
  const float* wo     = (const float*)d_in[13];
  const float* bo     = (const float*)d_in[14];
  float* out = (float*)d_out;

  char* ws = (char*)d_ws;
  const size_t MiB = 1u << 20;
  u16* zbb     = (u16*)(ws);                        // 1 MiB  [h][col>>2][q][col&3] bf16
  u16* wcat_t  = (u16*)(ws + 2 * MiB);              // 512 KiB
  u16* wot     = (u16*)(ws + 2 * MiB + 512 * 1024); // 128 KiB
  u16* mln     = (u16*)(ws + 3 * MiB);              // 16 MiB
  u16* qb      = (u16*)(ws + 19 * MiB);             // 16 MiB  [s][h][r][d]
  u16* kb      = (u16*)(ws + 35 * MiB);             // 16 MiB  [s][h][r][d]
  u16* vt      = (u16*)(ws + 51 * MiB);             // 16 MiB  V frag layout
  u16* gb      = (u16*)(ws + 67 * MiB);             // 16 MiB  [row][hd]
  u16* ogb     = (u16*)(ws + 83 * MiB);             // 16 MiB  [row][hd]
  (void)in_sizes; (void)n_in; (void)out_size; (void)ws_size;

  k_prep<<<dim3(16, 5), 256, 0, stream>>>(wq, wk, wv, wg, wo, wcat_t, wot);
  k_zbias<<<(R * R) / 32, 256, 0, stream>>>(z, ln_z_g, ln_z_b, wz, zbb);
  k_lnm<<<(S * R) / 4, 256, 0, stream>>>(m, ln_m_g, ln_m_b, mln);
  k_proj<<<dim3(256, 8), 256, 0, stream>>>(mln, wcat_t, bg, qb, kb, vt, gb);
  k_attn<<<S * H * 2, 256, 0, stream>>>(qb, kb, vt, gb, zbb, mask, ogb);
  k_out<<<dim3(256, 2), 256, 0, stream>>>(ogb, wot, bo, out);
}

// Round 12
// 120.659 us; speedup vs baseline: 2.8421x; 1.0334x over previous
//
#include <hip/hip_runtime.h>
#include <hip/hip_bf16.h>
#include <stdint.h>

#define S 128
#define R 256
#define CM 256
#define CZ 128
#define H 8
#define D 32

typedef __attribute__((ext_vector_type(8))) short short8;
typedef __attribute__((ext_vector_type(4))) float f32x4;
typedef __attribute__((ext_vector_type(16))) float f32x16;
typedef __attribute__((ext_vector_type(2))) unsigned uint2v;
typedef unsigned short u16;

#define LOG2E 1.4426950408889634f

// ---------- helpers ----------
__device__ __forceinline__ float wsum(float v) {
#pragma unroll
  for (int o = 32; o > 0; o >>= 1) v += __shfl_xor(v, o, 64);
  return v;
}
__device__ __forceinline__ u16 f2bb(float f) {
  unsigned u = __float_as_uint(f);
  return (u16)((u + 0x7fffu + ((u >> 16) & 1u)) >> 16);
}
__device__ __forceinline__ float b2f(u16 u) {
  return __uint_as_float(((unsigned)u) << 16);
}
__device__ __forceinline__ unsigned pkbf16(float a, float b) {
  __hip_bfloat162 t = __float22bfloat162_rn(make_float2(a, b));
  union { __hip_bfloat162 h; unsigned u; } cv;
  cv.h = t;
  return cv.u;
}
__device__ __forceinline__ void gl_lds16(const u16* g, u16* l) {
  __builtin_amdgcn_global_load_lds(
      (const __attribute__((address_space(1))) unsigned int*)g,
      (__attribute__((address_space(3))) unsigned int*)l, 16, 0, 0);
}

// stage a [128 rows][64 cols] bf16 tile (src row stride 256 elems) into linear LDS.
__device__ __forceinline__ void stage_tile(const u16* __restrict__ src, u16* lbase,
                                           int w, int l) {
#pragma unroll
  for (int it = 0; it < 4; it++) {
    int rbase = it * 32 + w * 8;
    int row = rbase + (l >> 3);
    int gc8 = (l & 7) ^ (row & 7);
    gl_lds16(src + (size_t)row * 256 + gc8 * 8, lbase + rbase * 64);
  }
}

// ---------- kernel 1 (fused pre-stage): lnm | zbias | prep by blockIdx range ----------
// blocks [0, 8192): LN(m) -> bf16 mln
// blocks [8192, 10240): pair bias -> zbb[h][col>>2][q][col&3] (log2e folded)
// blocks [10240, 10320): weights -> bf16 transposed (qscale*log2e folded)
__global__ __launch_bounds__(256) void k_pre(const float* __restrict__ m,
                                             const float* __restrict__ ln_m_g,
                                             const float* __restrict__ ln_m_b,
                                             const float* __restrict__ z,
                                             const float* __restrict__ ln_z_g,
                                             const float* __restrict__ ln_z_b,
                                             const float* __restrict__ wz,
                                             const float* __restrict__ wq,
                                             const float* __restrict__ wk,
                                             const float* __restrict__ wv,
                                             const float* __restrict__ wg,
                                             const float* __restrict__ wo,
                                             u16* __restrict__ mln,
                                             u16* __restrict__ zbb,
                                             u16* __restrict__ wcat_t,
                                             u16* __restrict__ wot) {
  __shared__ float t[64][65];
  int bid = blockIdx.x;
  int tid = threadIdx.x;

  if (bid < 8192) {
    // ---- LN(m) -> bf16 ----
    int w = tid >> 6, lane = tid & 63;
    size_t row = (size_t)bid * 4 + w;
    const float4 v = *(const float4*)(m + row * 256 + lane * 4);
    float sum = wsum(v.x + v.y + v.z + v.w);
    float ssq = wsum(v.x * v.x + v.y * v.y + v.z * v.z + v.w * v.w);
    float mu = sum * (1.f / 256);
    float rs = rsqrtf(ssq * (1.f / 256) - mu * mu + 1e-5f);
    const float4 gg = *(const float4*)(ln_m_g + lane * 4);
    const float4 bb = *(const float4*)(ln_m_b + lane * 4);
    ushort4 o;
    o.x = f2bb((v.x - mu) * rs * gg.x + bb.x);
    o.y = f2bb((v.y - mu) * rs * gg.y + bb.y);
    o.z = f2bb((v.z - mu) * rs * gg.z + bb.z);
    o.w = f2bb((v.w - mu) * rs * gg.w + bb.w);
    *(ushort4*)(mln + row * 256 + lane * 4) = o;
    return;
  }

  if (bid < 10240) {
    // ---- pair bias -> interleaved bf16 ----
    int bx = bid - 8192;
    int l = tid & 63, w = tid >> 6;
    int psub = l >> 3, cg = l & 7;
    int op = bx * 32 + w * 8 + psub;   // op = q*256 + col (z pair index)
    const float* zr = z + (size_t)op * CZ;
    float4 v[4];
#pragma unroll
    for (int i = 0; i < 4; i++) v[i] = *(const float4*)(zr + i * 32 + cg * 4);
    float sum = 0.f, ssq = 0.f;
#pragma unroll
    for (int i = 0; i < 4; i++) {
      sum += v[i].x + v[i].y + v[i].z + v[i].w;
      ssq += v[i].x * v[i].x + v[i].y * v[i].y + v[i].z * v[i].z + v[i].w * v[i].w;
    }
    sum += __shfl_xor(sum, 1, 64); sum += __shfl_xor(sum, 2, 64); sum += __shfl_xor(sum, 4, 64);
    ssq += __shfl_xor(ssq, 1, 64); ssq += __shfl_xor(ssq, 2, 64); ssq += __shfl_xor(ssq, 4, 64);
    float mu = sum * (1.0f / CZ);
    float rs = rsqrtf(ssq * (1.0f / CZ) - mu * mu + 1e-5f);
    float ph[8];
#pragma unroll
    for (int hh = 0; hh < 8; hh++) ph[hh] = 0.f;
#pragma unroll
    for (int i = 0; i < 4; i++) {
      int c0 = i * 32 + cg * 4;
      float4 gg = *(const float4*)(ln_z_g + c0);
      float4 bb = *(const float4*)(ln_z_b + c0);
      float n0 = (v[i].x - mu) * rs * gg.x + bb.x;
      float n1 = (v[i].y - mu) * rs * gg.y + bb.y;
      float n2 = (v[i].z - mu) * rs * gg.z + bb.z;
      float n3 = (v[i].w - mu) * rs * gg.w + bb.w;
#pragma unroll
      for (int jj = 0; jj < 4; jj++) {
        float nj = (jj == 0) ? n0 : (jj == 1) ? n1 : (jj == 2) ? n2 : n3;
        float4 w0 = *(const float4*)(wz + (c0 + jj) * 8);
        float4 w1 = *(const float4*)(wz + (c0 + jj) * 8 + 4);
        ph[0] = fmaf(nj, w0.x, ph[0]); ph[1] = fmaf(nj, w0.y, ph[1]);
        ph[2] = fmaf(nj, w0.z, ph[2]); ph[3] = fmaf(nj, w0.w, ph[3]);
        ph[4] = fmaf(nj, w1.x, ph[4]); ph[5] = fmaf(nj, w1.y, ph[5]);
        ph[6] = fmaf(nj, w1.z, ph[6]); ph[7] = fmaf(nj, w1.w, ph[7]);
      }
    }
    float a[4];
#pragma unroll
    for (int j = 0; j < 4; j++) {
      float keep = (l & 1) ? ph[4 + j] : ph[j];
      float send = (l & 1) ? ph[j] : ph[4 + j];
      a[j] = keep + __shfl_xor(send, 1, 64);
    }
    float b2[2];
#pragma unroll
    for (int j = 0; j < 2; j++) {
      float keep = (l & 2) ? a[2 + j] : a[j];
      float send = (l & 2) ? a[j] : a[2 + j];
      b2[j] = keep + __shfl_xor(send, 2, 64);
    }
    float keep = (l & 4) ? b2[1] : b2[0];
    float send = (l & 4) ? b2[0] : b2[1];
    float c = keep + __shfl_xor(send, 4, 64);
    int hh = 4 * (l & 1) + (l & 2) + ((l & 4) >> 2);
    int q = op >> 8, col = op & 255;
    zbb[(size_t)hh * 65536 + (size_t)(col >> 2) * 1024 + q * 4 + (col & 3)] = f2bb(c * LOG2E);
    return;
  }

  // ---- weight prep ----
  int bid2 = bid - 10240;
  int mat = bid2 >> 4;   // 0..4
  int bx = bid2 & 15;
  const float* src = (mat == 0) ? wq : (mat == 1) ? wk : (mat == 2) ? wv
                     : (mat == 3) ? wg : wo;
  float scale = (mat == 0) ? 0.17677669529663687f * LOG2E : 1.0f;
  u16* dst = (mat < 4) ? (wcat_t + mat * 256 * 256) : wot;
  int ti = bx >> 2, tj = bx & 3;
  int cc = tid & 63, rr4 = tid >> 6;
#pragma unroll
  for (int it = 0; it < 16; it++) {
    int ic = it * 4 + rr4;
    t[ic][cc] = src[(tj * 64 + ic) * 256 + ti * 64 + cc];
  }
  __syncthreads();
#pragma unroll
  for (int it = 0; it < 16; it++) {
    int oh = it * 4 + rr4;
    dst[(ti * 64 + oh) * 256 + tj * 64 + cc] = f2bb(t[cc][oh] * scale);
  }
}

// ---------- kernel 3: 128x128-tile MFMA GEMM  mln @ Wcat -> q/k/vfrag/g ----------
__global__ __launch_bounds__(256) void k_proj(const u16* __restrict__ mln,
                                              const u16* __restrict__ wcat_t,
                                              const float* __restrict__ bg,
                                              u16* __restrict__ qb,
                                              u16* __restrict__ kbuf,
                                              u16* __restrict__ vt,
                                              u16* __restrict__ gb) {
  __shared__ __align__(16) u16 lds[4 * 8192];  // A0 A1 B0 B1 (16KB each)
  int tid = threadIdx.x;
  int w = tid >> 6, l = tid & 63;
  int l15 = l & 15, lg = l >> 4;
  int wr = w >> 1, wc = w & 1;
  int grow0 = blockIdx.x * 128;
  int hdt0 = blockIdx.y * 128;
  const u16* asrc = mln + (size_t)grow0 * 256;
  const u16* bsrc = wcat_t + (size_t)hdt0 * 256;

  stage_tile(asrc, lds, w, l);
  stage_tile(bsrc, lds + 16384, w, l);
  __syncthreads();

  f32x4 acc[4][4];
#pragma unroll
  for (int mi = 0; mi < 4; mi++)
#pragma unroll
    for (int ni = 0; ni < 4; ni++) acc[mi][ni] = (f32x4){0.f, 0.f, 0.f, 0.f};

#pragma unroll
  for (int kt = 0; kt < 4; kt++) {
    if (kt < 3) {
      stage_tile(asrc + (kt + 1) * 64, lds + ((kt + 1) & 1) * 8192, w, l);
      stage_tile(bsrc + (kt + 1) * 64, lds + 16384 + ((kt + 1) & 1) * 8192, w, l);
    }
    const u16* Ab = lds + (kt & 1) * 8192;
    const u16* Bb = lds + 16384 + (kt & 1) * 8192;
#pragma unroll
    for (int ks = 0; ks < 2; ks++) {
      short8 af[4], bf[4];
#pragma unroll
      for (int i = 0; i < 4; i++) {
        int ra = wr * 64 + i * 16 + l15;
        af[i] = *(const short8*)(Ab + ra * 64 + (((ks * 4 + lg) ^ (ra & 7)) << 3));
        int rb = wc * 64 + i * 16 + l15;
        bf[i] = *(const short8*)(Bb + rb * 64 + (((ks * 4 + lg) ^ (rb & 7)) << 3));
      }
#pragma unroll
      for (int mi = 0; mi < 4; mi++)
#pragma unroll
        for (int ni = 0; ni < 4; ni++)
          acc[mi][ni] =
              __builtin_amdgcn_mfma_f32_16x16x32_bf16(af[mi], bf[ni], acc[mi][ni], 0, 0, 0);
    }
    __syncthreads();
  }

  // ---- epilogue: re-stage through LDS for coalesced uint4 stores ----
  int by = blockIdx.y;
  int mat = by >> 1;            // 0:q 1:k 2:v(frag layout) 3:g
  int s = grow0 >> 8, r0 = grow0 & 255;
  int hbase = (by & 1) * 128;
  u16* stg = lds;               // [128][136] bf16

  if (mat == 2) {
    // stage transposed: stg[hd_loc][k_loc]
#pragma unroll
    for (int mi = 0; mi < 4; mi++)
#pragma unroll
      for (int ni = 0; ni < 4; ni++)
#pragma unroll
        for (int j = 0; j < 4; j++) {
          int rl = wr * 64 + mi * 16 + lg * 4 + j;
          int hl = wc * 64 + ni * 16 + l15;
          stg[hl * 136 + rl] = f2bb(acc[mi][ni][j]);
        }
    __syncthreads();
    // frag layout: vt[((s*8+h)*16 + k16)*512 + l5*256 + d*8 + (k&7)]
#pragma unroll
    for (int it = 0; it < 8; it++) {
      int idx = it * 256 + tid;
      int hd_l = idx & 127, k8 = idx >> 7;      // k8: 0..15 (8-element k chunk)
      uint4 val = *(const uint4*)(stg + hd_l * 136 + k8 * 8);
      int hd = hbase + hd_l;
      int h = hd >> 5, d = hd & 31;
      int kg = r0 + k8 * 8;
      size_t off = (((size_t)(s * 8 + h) * 16 + (kg >> 4)) * 2 + ((kg >> 3) & 1)) * 256 + d * 8;
      *(uint4*)(vt + off) = val;
    }
  } else {
    float bgv[4];
    if (mat == 3) {
#pragma unroll
      for (int ni = 0; ni < 4; ni++) bgv[ni] = bg[hbase + wc * 64 + ni * 16 + l15];
    }
#pragma unroll
    for (int mi = 0; mi < 4; mi++)
#pragma unroll
      for (int ni = 0; ni < 4; ni++)
#pragma unroll
        for (int j = 0; j < 4; j++) {
          int rl = wr * 64 + mi * 16 + lg * 4 + j;
          int hl = wc * 64 + ni * 16 + l15;
          float v = acc[mi][ni][j];
          if (mat == 3) v = 1.0f / (1.0f + __expf(-(v + bgv[ni])));
          stg[rl * 136 + hl] = f2bb(v);
        }
    __syncthreads();
#pragma unroll
    for (int it = 0; it < 8; it++) {
      int idx = it * 256 + tid;
      int rl = idx >> 4, c = idx & 15;
      uint4 val = *(const uint4*)(stg + rl * 136 + c * 8);
      int hd = hbase + c * 8;
      if (mat == 3) {
        *(uint4*)(gb + (size_t)(grow0 + rl) * 256 + hd) = val;
      } else {
        u16* dst = (mat == 0) ? qb : kbuf;
        *(uint4*)(dst + ((size_t)(s * 8 + (hd >> 5)) * 256 + r0 + rl) * 32 + (hd & 31)) = val;
      }
    }
  }
}

// ---------- kernel 4: swapped-QK 32x32 MFMA flash attention, register softmax ----------
// Grid: S*H*2 blocks; each wave owns ONE 32-q-row tile (low register pressure, no spill).
__global__ __launch_bounds__(256) void k_attn(const u16* __restrict__ qb,
                                              const u16* __restrict__ kbuf,
                                              const u16* __restrict__ vt,
                                              const u16* __restrict__ gb,
                                              const u16* __restrict__ zbb,
                                              const float* __restrict__ mask,
                                              u16* __restrict__ og) {
  __shared__ float mbl[256];            // mask bias, log2e folded
  int blk = blockIdx.x;                 // s*16 + h*2 + half
  int s = blk >> 4, h = (blk >> 1) & 7, half = blk & 1;
  int tid = threadIdx.x, w = tid >> 6, l = tid & 63;
  int l31 = l & 31, l5 = l >> 5;
  int q0 = half * 128 + w * 32;
  size_t base = (size_t)(s * 8 + h) * 256 * 32;
  const u16* zb4 = zbb + (size_t)h * 65536;   // [col>>2][q][col&3] bf16, log2e folded

  mbl[tid] = (LOG2E * 1e9f) * (mask[s * 256 + tid] - 1.0f);

  // Q B-frags: Q[q0+l31][dh*16 + l5*8 ..+7]
  short8 qf[2];
#pragma unroll
  for (int dh = 0; dh < 2; dh++)
    qf[dh] = *(const short8*)(qb + base + (size_t)(q0 + l31) * 32 + dh * 16 + l5 * 8);

  f32x16 oacc;
#pragma unroll
  for (int j = 0; j < 16; j++) oacc[j] = 0.f;
  float ls0 = 0.f, ls1 = 0.f;
  __syncthreads();

#pragma unroll
  for (int kb = 0; kb < 4; kb++) {
    int kbase = kb * 64;
    // K A-frags: K[kbase+kt*32+l31][dh*16 + l5*8..]
    short8 kf[2][2];
#pragma unroll
    for (int kt = 0; kt < 2; kt++)
#pragma unroll
      for (int dh = 0; dh < 2; dh++)
        kf[kt][dh] = *(const short8*)(kbuf + base + (size_t)(kbase + kt * 32 + l31) * 32 +
                                      dh * 16 + l5 * 8);
    // V B-frags from frag layout: fully coalesced (16B/lane)
    short8 vf[2][2];
#pragma unroll
    for (int kt = 0; kt < 2; kt++)
#pragma unroll
      for (int ks = 0; ks < 2; ks++)
        vf[kt][ks] = *(const short8*)(vt + ((size_t)(s * 8 + h) * 16 +
                                            (kb * 4 + kt * 2 + ks)) * 512 +
                                      l5 * 256 + l31 * 8);

#pragma unroll
    for (int kt = 0; kt < 2; kt++) {
      // ---- C-init: vectorized z (ushort4 = 4 cols) + LDS mask bias
      f32x16 c;
#pragma unroll
      for (int cc = 0; cc < 4; cc++) {
        int col0 = kbase + kt * 32 + cc * 8 + l5 * 4;
        ushort4 zu = *(const ushort4*)(zb4 + ((size_t)(col0 >> 2) << 10) + ((q0 + l31) << 2));
        float4 mv = *(const float4*)(mbl + col0);
        c[4 * cc + 0] = b2f(zu.x) + mv.x;
        c[4 * cc + 1] = b2f(zu.y) + mv.y;
        c[4 * cc + 2] = b2f(zu.z) + mv.z;
        c[4 * cc + 3] = b2f(zu.w) + mv.w;
      }
      // ---- S^T = K @ Q^T + C  (lane: col=q, rows=k)
      c = __builtin_amdgcn_mfma_f32_32x32x16_bf16(kf[kt][0], qf[0], c, 0, 0, 0);
      c = __builtin_amdgcn_mfma_f32_32x32x16_bf16(kf[kt][1], qf[1], c, 0, 0, 0);
      // ---- p = exp2(c); row-sum partials
      float p[16];
#pragma unroll
      for (int j = 0; j < 16; j++) {
        p[j] = __builtin_amdgcn_exp2f(c[j]);
        if (j & 1) ls1 += p[j]; else ls0 += p[j];
      }
      // ---- pack to bf16 words (compiler-managed cvt_pk + permlane)
      unsigned wd[8];
#pragma unroll
      for (int r = 0; r < 8; r++) wd[r] = pkbf16(p[2 * r], p[2 * r + 1]);
      {
        uint2v r0 = __builtin_amdgcn_permlane32_swap(wd[0], wd[2], false, false);
        wd[0] = r0[0]; wd[2] = r0[1];
        uint2v r1 = __builtin_amdgcn_permlane32_swap(wd[1], wd[3], false, false);
        wd[1] = r1[0]; wd[3] = r1[1];
        uint2v r2 = __builtin_amdgcn_permlane32_swap(wd[4], wd[6], false, false);
        wd[4] = r2[0]; wd[6] = r2[1];
        uint2v r3 = __builtin_amdgcn_permlane32_swap(wd[5], wd[7], false, false);
        wd[5] = r3[0]; wd[7] = r3[1];
      }
      union { unsigned u[4]; short8 s8; } pa0, pa1;
      pa0.u[0] = wd[0]; pa0.u[1] = wd[1]; pa0.u[2] = wd[2]; pa0.u[3] = wd[3];
      pa1.u[0] = wd[4]; pa1.u[1] = wd[5]; pa1.u[2] = wd[6]; pa1.u[3] = wd[7];
      // ---- O[q][d] += P @ V
      oacc = __builtin_amdgcn_mfma_f32_32x32x16_bf16(pa0.s8, vf[kt][0], oacc, 0, 0, 0);
      oacc = __builtin_amdgcn_mfma_f32_32x32x16_bf16(pa1.s8, vf[kt][1], oacc, 0, 0, 0);
    }
  }
  // ---- finalize row sums (lane holds q=l31; halves hold disjoint k-sets)
  float lv = ls0 + ls1;
  lv += __shfl_xor(lv, 32, 64);
  float inv = 1.0f / lv;
  // ---- normalize, gate, store (O layout: col=l31=d, row q = (j&3)+8*(j>>2)+4*l5)
#pragma unroll
  for (int j = 0; j < 16; j++) {
    int qrow = (j & 3) + 8 * (j >> 2) + 4 * l5;
    float invj = __shfl(inv, qrow, 64);
    int q = q0 + qrow;
    size_t ob = ((size_t)s * 256 + q) * 256 + h * 32 + l31;
    float gv = b2f(gb[ob]);
    og[ob] = f2bb(oacc[j] * invj * gv);
  }
}

// ---------- kernel 5: 128x128-tile MFMA GEMM  og @ WO + bo -> out f32 ----------
__global__ __launch_bounds__(256) void k_out(const u16* __restrict__ og,
                                             const u16* __restrict__ wot,
                                             const float* __restrict__ bo,
                                             float* __restrict__ out) {
  __shared__ __align__(16) u16 lds[4 * 8192];
  int tid = threadIdx.x;
  int w = tid >> 6, l = tid & 63;
  int l15 = l & 15, lg = l >> 4;
  int wr = w >> 1, wc = w & 1;
  int grow0 = blockIdx.x * 128;
  int ct0 = blockIdx.y * 128;
  const u16* asrc = og + (size_t)grow0 * 256;
  const u16* bsrc = wot + (size_t)ct0 * 256;

  stage_tile(asrc, lds, w, l);
  stage_tile(bsrc, lds + 16384, w, l);
  __syncthreads();

  f32x4 acc[4][4];
#pragma unroll
  for (int mi = 0; mi < 4; mi++)
#pragma unroll
    for (int ni = 0; ni < 4; ni++) acc[mi][ni] = (f32x4){0.f, 0.f, 0.f, 0.f};

#pragma unroll
  for (int kt = 0; kt < 4; kt++) {
    if (kt < 3) {
      stage_tile(asrc + (kt + 1) * 64, lds + ((kt + 1) & 1) * 8192, w, l);
      stage_tile(bsrc + (kt + 1) * 64, lds + 16384 + ((kt + 1) & 1) * 8192, w, l);
    }
    const u16* Ab = lds + (kt & 1) * 8192;
    const u16* Bb = lds + 16384 + (kt & 1) * 8192;
#pragma unroll
    for (int ks = 0; ks < 2; ks++) {
      short8 af[4], bf[4];
#pragma unroll
      for (int i = 0; i < 4; i++) {
        int ra = wr * 64 + i * 16 + l15;
        af[i] = *(const short8*)(Ab + ra * 64 + (((ks * 4 + lg) ^ (ra & 7)) << 3));
        int rb = wc * 64 + i * 16 + l15;
        bf[i] = *(const short8*)(Bb + rb * 64 + (((ks * 4 + lg) ^ (rb & 7)) << 3));
      }
#pragma unroll
      for (int mi = 0; mi < 4; mi++)
#pragma unroll
        for (int ni = 0; ni < 4; ni++)
          acc[mi][ni] =
              __builtin_amdgcn_mfma_f32_16x16x32_bf16(af[mi], bf[ni], acc[mi][ni], 0, 0, 0);
    }
    __syncthreads();
  }

  int cout_base = ct0 + wc * 64;
#pragma unroll
  for (int ni = 0; ni < 4; ni++) {
    int cout = cout_base + ni * 16 + l15;
    float bov = bo[cout];
#pragma unroll
    for (int mi = 0; mi < 4; mi++)
#pragma unroll
      for (int j = 0; j < 4; j++)
        out[(size_t)(grow0 + wr * 64 + mi * 16 + lg * 4 + j) * 256 + cout] =
            acc[mi][ni][j] + bov;
  }
}

extern "C" void kernel_launch(void* const* d_in, const int* in_sizes, int n_in,
                              void* d_out, int out_size, void* d_ws, size_t ws_size,
                              hipStream_t stream) {
  const float* m      = (const float*)d_in[0];
  const float* z      = (const float*)d_in[1];
  const float* mask   = (const float*)d_in[2];
  const float* ln_m_g = (const float*)d_in[3];
  const float* ln_m_b = (const float*)d_in[4];
  const float* ln_z_g = (const float*)d_in[5];
  const float* ln_z_b = (const float*)d_in[6];
  const float* wz     = (const float*)d_in[7];
  const float* wq     = (const float*)d_in[8];
  const float* wk     = (const float*)d_in[9];
  const float* wv     = (const float*)d_in[10];
  const float* wg     = (const float*)d_in[11];
  const float* bg     = (const float*)d_in[12];
  const float* wo     = (const float*)d_in[13];
  const float* bo     = (const float*)d_in[14];
  float* out = (float*)d_out;

  char* ws = (char*)d_ws;
  const size_t MiB = 1u << 20;
  u16* zbb     = (u16*)(ws);                        // 1 MiB  [h][col>>2][q][col&3] bf16
  u16* wcat_t  = (u16*)(ws + 2 * MiB);              // 512 KiB
  u16* wot     = (u16*)(ws + 2 * MiB + 512 * 1024); // 128 KiB
  u16* mln     = (u16*)(ws + 3 * MiB);              // 16 MiB
  u16* qb      = (u16*)(ws + 19 * MiB);             // 16 MiB  [s][h][r][d]
  u16* kb      = (u16*)(ws + 35 * MiB);             // 16 MiB  [s][h][r][d]
  u16* vt      = (u16*)(ws + 51 * MiB);             // 16 MiB  V frag layout
  u16* gb      = (u16*)(ws + 67 * MiB);             // 16 MiB  [row][hd]
  u16* ogb     = (u16*)(ws + 83 * MiB);             // 16 MiB  [row][hd]
  (void)in_sizes; (void)n_in; (void)out_size; (void)ws_size;

  k_pre<<<10320, 256, 0, stream>>>(m, ln_m_g, ln_m_b, z, ln_z_g, ln_z_b, wz,
                                   wq, wk, wv, wg, wo, mln, zbb, wcat_t, wot);
  k_proj<<<dim3(256, 8), 256, 0, stream>>>(mln, wcat_t, bg, qb, kb, vt, gb);
  k_attn<<<S * H * 2, 256, 0, stream>>>(qb, kb, vt, gb, zbb, mask, ogb);
  k_out<<<dim3(256, 2), 256, 0, stream>>>(ogb, wot, bo, out);
}

// Round 13
// 119.034 us; speedup vs baseline: 2.8809x; 1.0137x over previous
//
#include <hip/hip_runtime.h>
#include <hip/hip_bf16.h>
#include <stdint.h>

#define S 128
#define R 256
#define CM 256
#define CZ 128
#define H 8
#define D 32

typedef __attribute__((ext_vector_type(8))) short short8;
typedef __attribute__((ext_vector_type(4))) float f32x4;
typedef __attribute__((ext_vector_type(16))) float f32x16;
typedef __attribute__((ext_vector_type(2))) unsigned uint2v;
typedef unsigned short u16;

#define LOG2E 1.4426950408889634f

// ---------- helpers ----------
__device__ __forceinline__ float wsum(float v) {
#pragma unroll
  for (int o = 32; o > 0; o >>= 1) v += __shfl_xor(v, o, 64);
  return v;
}
__device__ __forceinline__ u16 f2bb(float f) {
  unsigned u = __float_as_uint(f);
  return (u16)((u + 0x7fffu + ((u >> 16) & 1u)) >> 16);
}
__device__ __forceinline__ float b2f(u16 u) {
  return __uint_as_float(((unsigned)u) << 16);
}
__device__ __forceinline__ unsigned pkbf16(float a, float b) {
  __hip_bfloat162 t = __float22bfloat162_rn(make_float2(a, b));
  union { __hip_bfloat162 h; unsigned u; } cv;
  cv.h = t;
  return cv.u;
}
__device__ __forceinline__ void gl_lds16(const u16* g, u16* l) {
  __builtin_amdgcn_global_load_lds(
      (const __attribute__((address_space(1))) unsigned int*)g,
      (__attribute__((address_space(3))) unsigned int*)l, 16, 0, 0);
}

// stage a [128 rows][64 cols] bf16 tile (src row stride 256 elems) into linear LDS.
__device__ __forceinline__ void stage_tile(const u16* __restrict__ src, u16* lbase,
                                           int w, int l) {
#pragma unroll
  for (int it = 0; it < 4; it++) {
    int rbase = it * 32 + w * 8;
    int row = rbase + (l >> 3);
    int gc8 = (l & 7) ^ (row & 7);
    gl_lds16(src + (size_t)row * 256 + gc8 * 8, lbase + rbase * 64);
  }
}

// ---------- kernel 1 (fused pre-stage): lnm | zbias | prep by blockIdx range ----------
// blocks [0, 2048): LN(m) -> bf16 mln  (16 rows/block, 16 lanes/row)
// blocks [2048, 4096): pair bias -> zbb[h][col>>2][q][col&3] (log2e folded)
// blocks [4096, 4176): weights -> bf16 transposed (qscale*log2e folded)
__global__ __launch_bounds__(256) void k_pre(const float* __restrict__ m,
                                             const float* __restrict__ ln_m_g,
                                             const float* __restrict__ ln_m_b,
                                             const float* __restrict__ z,
                                             const float* __restrict__ ln_z_g,
                                             const float* __restrict__ ln_z_b,
                                             const float* __restrict__ wz,
                                             const float* __restrict__ wq,
                                             const float* __restrict__ wk,
                                             const float* __restrict__ wv,
                                             const float* __restrict__ wg,
                                             const float* __restrict__ wo,
                                             u16* __restrict__ mln,
                                             u16* __restrict__ zbb,
                                             u16* __restrict__ wcat_t,
                                             u16* __restrict__ wot) {
  __shared__ float t[64][65];
  int bid = blockIdx.x;
  int tid = threadIdx.x;

  if (bid < 2048) {
    // ---- LN(m) -> bf16: 16 rows/block, 16 lanes/row, 64B/lane ----
    int grp = tid >> 4, l15 = tid & 15;
    size_t row = (size_t)bid * 16 + grp;
    const float* mr = m + row * 256 + l15 * 4;
    float4 v[4];
#pragma unroll
    for (int i = 0; i < 4; i++) v[i] = *(const float4*)(mr + i * 64);
    float sum = 0.f, ssq = 0.f;
#pragma unroll
    for (int i = 0; i < 4; i++) {
      sum += v[i].x + v[i].y + v[i].z + v[i].w;
      ssq += v[i].x * v[i].x + v[i].y * v[i].y + v[i].z * v[i].z + v[i].w * v[i].w;
    }
    sum += __shfl_xor(sum, 1, 64); sum += __shfl_xor(sum, 2, 64);
    sum += __shfl_xor(sum, 4, 64); sum += __shfl_xor(sum, 8, 64);
    ssq += __shfl_xor(ssq, 1, 64); ssq += __shfl_xor(ssq, 2, 64);
    ssq += __shfl_xor(ssq, 4, 64); ssq += __shfl_xor(ssq, 8, 64);
    float mu = sum * (1.f / 256);
    float rs = rsqrtf(ssq * (1.f / 256) - mu * mu + 1e-5f);
#pragma unroll
    for (int i = 0; i < 4; i++) {
      const float4 gg = *(const float4*)(ln_m_g + l15 * 4 + i * 64);
      const float4 bb = *(const float4*)(ln_m_b + l15 * 4 + i * 64);
      ushort4 o;
      o.x = f2bb((v[i].x - mu) * rs * gg.x + bb.x);
      o.y = f2bb((v[i].y - mu) * rs * gg.y + bb.y);
      o.z = f2bb((v[i].z - mu) * rs * gg.z + bb.z);
      o.w = f2bb((v[i].w - mu) * rs * gg.w + bb.w);
      *(ushort4*)(mln + row * 256 + i * 64 + l15 * 4) = o;
    }
    return;
  }

  if (bid < 4096) {
    // ---- pair bias -> interleaved bf16 ----
    int bx = bid - 2048;
    int l = tid & 63, w = tid >> 6;
    int psub = l >> 3, cg = l & 7;
    int op = bx * 32 + w * 8 + psub;   // op = q*256 + col (z pair index)
    const float* zr = z + (size_t)op * CZ;
    float4 v[4];
#pragma unroll
    for (int i = 0; i < 4; i++) v[i] = *(const float4*)(zr + i * 32 + cg * 4);
    float sum = 0.f, ssq = 0.f;
#pragma unroll
    for (int i = 0; i < 4; i++) {
      sum += v[i].x + v[i].y + v[i].z + v[i].w;
      ssq += v[i].x * v[i].x + v[i].y * v[i].y + v[i].z * v[i].z + v[i].w * v[i].w;
    }
    sum += __shfl_xor(sum, 1, 64); sum += __shfl_xor(sum, 2, 64); sum += __shfl_xor(sum, 4, 64);
    ssq += __shfl_xor(ssq, 1, 64); ssq += __shfl_xor(ssq, 2, 64); ssq += __shfl_xor(ssq, 4, 64);
    float mu = sum * (1.0f / CZ);
    float rs = rsqrtf(ssq * (1.0f / CZ) - mu * mu + 1e-5f);
    float ph[8];
#pragma unroll
    for (int hh = 0; hh < 8; hh++) ph[hh] = 0.f;
#pragma unroll
    for (int i = 0; i < 4; i++) {
      int c0 = i * 32 + cg * 4;
      float4 gg = *(const float4*)(ln_z_g + c0);
      float4 bb = *(const float4*)(ln_z_b + c0);
      float n0 = (v[i].x - mu) * rs * gg.x + bb.x;
      float n1 = (v[i].y - mu) * rs * gg.y + bb.y;
      float n2 = (v[i].z - mu) * rs * gg.z + bb.z;
      float n3 = (v[i].w - mu) * rs * gg.w + bb.w;
#pragma unroll
      for (int jj = 0; jj < 4; jj++) {
        float nj = (jj == 0) ? n0 : (jj == 1) ? n1 : (jj == 2) ? n2 : n3;
        float4 w0 = *(const float4*)(wz + (c0 + jj) * 8);
        float4 w1 = *(const float4*)(wz + (c0 + jj) * 8 + 4);
        ph[0] = fmaf(nj, w0.x, ph[0]); ph[1] = fmaf(nj, w0.y, ph[1]);
        ph[2] = fmaf(nj, w0.z, ph[2]); ph[3] = fmaf(nj, w0.w, ph[3]);
        ph[4] = fmaf(nj, w1.x, ph[4]); ph[5] = fmaf(nj, w1.y, ph[5]);
        ph[6] = fmaf(nj, w1.z, ph[6]); ph[7] = fmaf(nj, w1.w, ph[7]);
      }
    }
    float a[4];
#pragma unroll
    for (int j = 0; j < 4; j++) {
      float keep = (l & 1) ? ph[4 + j] : ph[j];
      float send = (l & 1) ? ph[j] : ph[4 + j];
      a[j] = keep + __shfl_xor(send, 1, 64);
    }
    float b2[2];
#pragma unroll
    for (int j = 0; j < 2; j++) {
      float keep = (l & 2) ? a[2 + j] : a[j];
      float send = (l & 2) ? a[j] : a[2 + j];
      b2[j] = keep + __shfl_xor(send, 2, 64);
    }
    float keep = (l & 4) ? b2[1] : b2[0];
    float send = (l & 4) ? b2[0] : b2[1];
    float c = keep + __shfl_xor(send, 4, 64);
    int hh = 4 * (l & 1) + (l & 2) + ((l & 4) >> 2);
    int q = op >> 8, col = op & 255;
    zbb[(size_t)hh * 65536 + (size_t)(col >> 2) * 1024 + q * 4 + (col & 3)] = f2bb(c * LOG2E);
    return;
  }

  // ---- weight prep ----
  int bid2 = bid - 4096;
  int mat = bid2 >> 4;   // 0..4
  int bx = bid2 & 15;
  const float* src = (mat == 0) ? wq : (mat == 1) ? wk : (mat == 2) ? wv
                     : (mat == 3) ? wg : wo;
  float scale = (mat == 0) ? 0.17677669529663687f * LOG2E : 1.0f;
  u16* dst = (mat < 4) ? (wcat_t + mat * 256 * 256) : wot;
  int ti = bx >> 2, tj = bx & 3;
  int cc = tid & 63, rr4 = tid >> 6;
#pragma unroll
  for (int it = 0; it < 16; it++) {
    int ic = it * 4 + rr4;
    t[ic][cc] = src[(tj * 64 + ic) * 256 + ti * 64 + cc];
  }
  __syncthreads();
#pragma unroll
  for (int it = 0; it < 16; it++) {
    int oh = it * 4 + rr4;
    dst[(ti * 64 + oh) * 256 + tj * 64 + cc] = f2bb(t[cc][oh] * scale);
  }
}

// ---------- kernel 3: 128x128-tile MFMA GEMM  mln @ Wcat -> q/k/vfrag/g ----------
__global__ __launch_bounds__(256) void k_proj(const u16* __restrict__ mln,
                                              const u16* __restrict__ wcat_t,
                                              const float* __restrict__ bg,
                                              u16* __restrict__ qb,
                                              u16* __restrict__ kbuf,
                                              u16* __restrict__ vt,
                                              u16* __restrict__ gb) {
  __shared__ __align__(16) u16 lds[4 * 8192];  // A0 A1 B0 B1 (16KB each)
  int tid = threadIdx.x;
  int w = tid >> 6, l = tid & 63;
  int l15 = l & 15, lg = l >> 4;
  int wr = w >> 1, wc = w & 1;
  int grow0 = blockIdx.x * 128;
  int hdt0 = blockIdx.y * 128;
  const u16* asrc = mln + (size_t)grow0 * 256;
  const u16* bsrc = wcat_t + (size_t)hdt0 * 256;

  stage_tile(asrc, lds, w, l);
  stage_tile(bsrc, lds + 16384, w, l);
  __syncthreads();

  f32x4 acc[4][4];
#pragma unroll
  for (int mi = 0; mi < 4; mi++)
#pragma unroll
    for (int ni = 0; ni < 4; ni++) acc[mi][ni] = (f32x4){0.f, 0.f, 0.f, 0.f};

#pragma unroll
  for (int kt = 0; kt < 4; kt++) {
    if (kt < 3) {
      stage_tile(asrc + (kt + 1) * 64, lds + ((kt + 1) & 1) * 8192, w, l);
      stage_tile(bsrc + (kt + 1) * 64, lds + 16384 + ((kt + 1) & 1) * 8192, w, l);
    }
    const u16* Ab = lds + (kt & 1) * 8192;
    const u16* Bb = lds + 16384 + (kt & 1) * 8192;
#pragma unroll
    for (int ks = 0; ks < 2; ks++) {
      short8 af[4], bf[4];
#pragma unroll
      for (int i = 0; i < 4; i++) {
        int ra = wr * 64 + i * 16 + l15;
        af[i] = *(const short8*)(Ab + ra * 64 + (((ks * 4 + lg) ^ (ra & 7)) << 3));
        int rb = wc * 64 + i * 16 + l15;
        bf[i] = *(const short8*)(Bb + rb * 64 + (((ks * 4 + lg) ^ (rb & 7)) << 3));
      }
#pragma unroll
      for (int mi = 0; mi < 4; mi++)
#pragma unroll
        for (int ni = 0; ni < 4; ni++)
          acc[mi][ni] =
              __builtin_amdgcn_mfma_f32_16x16x32_bf16(af[mi], bf[ni], acc[mi][ni], 0, 0, 0);
    }
    __syncthreads();
  }

  // ---- epilogue: re-stage through LDS for coalesced uint4 stores ----
  int by = blockIdx.y;
  int mat = by >> 1;            // 0:q 1:k 2:v(frag layout) 3:g
  int s = grow0 >> 8, r0 = grow0 & 255;
  int hbase = (by & 1) * 128;
  u16* stg = lds;               // [128][136] bf16

  if (mat == 2) {
    // stage transposed: stg[hd_loc][k_loc]
#pragma unroll
    for (int mi = 0; mi < 4; mi++)
#pragma unroll
      for (int ni = 0; ni < 4; ni++)
#pragma unroll
        for (int j = 0; j < 4; j++) {
          int rl = wr * 64 + mi * 16 + lg * 4 + j;
          int hl = wc * 64 + ni * 16 + l15;
          stg[hl * 136 + rl] = f2bb(acc[mi][ni][j]);
        }
    __syncthreads();
    // frag layout: vt[((s*8+h)*16 + k16)*512 + l5*256 + d*8 + (k&7)]
#pragma unroll
    for (int it = 0; it < 8; it++) {
      int idx = it * 256 + tid;
      int hd_l = idx & 127, k8 = idx >> 7;      // k8: 0..15 (8-element k chunk)
      uint4 val = *(const uint4*)(stg + hd_l * 136 + k8 * 8);
      int hd = hbase + hd_l;
      int h = hd >> 5, d = hd & 31;
      int kg = r0 + k8 * 8;
      size_t off = (((size_t)(s * 8 + h) * 16 + (kg >> 4)) * 2 + ((kg >> 3) & 1)) * 256 + d * 8;
      *(uint4*)(vt + off) = val;
    }
  } else {
    float bgv[4];
    if (mat == 3) {
#pragma unroll
      for (int ni = 0; ni < 4; ni++) bgv[ni] = bg[hbase + wc * 64 + ni * 16 + l15];
    }
#pragma unroll
    for (int mi = 0; mi < 4; mi++)
#pragma unroll
      for (int ni = 0; ni < 4; ni++)
#pragma unroll
        for (int j = 0; j < 4; j++) {
          int rl = wr * 64 + mi * 16 + lg * 4 + j;
          int hl = wc * 64 + ni * 16 + l15;
          float v = acc[mi][ni][j];
          if (mat == 3) v = 1.0f / (1.0f + __expf(-(v + bgv[ni])));
          stg[rl * 136 + hl] = f2bb(v);
        }
    __syncthreads();
#pragma unroll
    for (int it = 0; it < 8; it++) {
      int idx = it * 256 + tid;
      int rl = idx >> 4, c = idx & 15;
      uint4 val = *(const uint4*)(stg + rl * 136 + c * 8);
      int hd = hbase + c * 8;
      if (mat == 3) {
        *(uint4*)(gb + (size_t)(grow0 + rl) * 256 + hd) = val;
      } else {
        u16* dst = (mat == 0) ? qb : kbuf;
        *(uint4*)(dst + ((size_t)(s * 8 + (hd >> 5)) * 256 + r0 + rl) * 32 + (hd & 31)) = val;
      }
    }
  }
}

// ---------- kernel 4: swapped-QK 32x32 MFMA flash attention, register softmax ----------
// Grid: S*H*2 blocks; each wave owns ONE 32-q-row tile (low register pressure, no spill).
__global__ __launch_bounds__(256) void k_attn(const u16* __restrict__ qb,
                                              const u16* __restrict__ kbuf,
                                              const u16* __restrict__ vt,
                                              const u16* __restrict__ gb,
                                              const u16* __restrict__ zbb,
                                              const float* __restrict__ mask,
                                              u16* __restrict__ og) {
  __shared__ float mbl[256];            // mask bias, log2e folded
  int blk = blockIdx.x;                 // s*16 + h*2 + half
  int s = blk >> 4, h = (blk >> 1) & 7, half = blk & 1;
  int tid = threadIdx.x, w = tid >> 6, l = tid & 63;
  int l31 = l & 31, l5 = l >> 5;
  int q0 = half * 128 + w * 32;
  size_t base = (size_t)(s * 8 + h) * 256 * 32;
  const u16* zb4 = zbb + (size_t)h * 65536;   // [col>>2][q][col&3] bf16, log2e folded

  mbl[tid] = (LOG2E * 1e9f) * (mask[s * 256 + tid] - 1.0f);

  // Q B-frags: Q[q0+l31][dh*16 + l5*8 ..+7]
  short8 qf[2];
#pragma unroll
  for (int dh = 0; dh < 2; dh++)
    qf[dh] = *(const short8*)(qb + base + (size_t)(q0 + l31) * 32 + dh * 16 + l5 * 8);

  f32x16 oacc;
#pragma unroll
  for (int j = 0; j < 16; j++) oacc[j] = 0.f;
  float ls0 = 0.f, ls1 = 0.f;
  __syncthreads();

#pragma unroll
  for (int kb = 0; kb < 4; kb++) {
    int kbase = kb * 64;
    // K A-frags: K[kbase+kt*32+l31][dh*16 + l5*8..]
    short8 kf[2][2];
#pragma unroll
    for (int kt = 0; kt < 2; kt++)
#pragma unroll
      for (int dh = 0; dh < 2; dh++)
        kf[kt][dh] = *(const short8*)(kbuf + base + (size_t)(kbase + kt * 32 + l31) * 32 +
                                      dh * 16 + l5 * 8);
    // V B-frags from frag layout: fully coalesced (16B/lane)
    short8 vf[2][2];
#pragma unroll
    for (int kt = 0; kt < 2; kt++)
#pragma unroll
      for (int ks = 0; ks < 2; ks++)
        vf[kt][ks] = *(const short8*)(vt + ((size_t)(s * 8 + h) * 16 +
                                            (kb * 4 + kt * 2 + ks)) * 512 +
                                      l5 * 256 + l31 * 8);

#pragma unroll
    for (int kt = 0; kt < 2; kt++) {
      // ---- C-init: vectorized z (ushort4 = 4 cols) + LDS mask bias
      f32x16 c;
#pragma unroll
      for (int cc = 0; cc < 4; cc++) {
        int col0 = kbase + kt * 32 + cc * 8 + l5 * 4;
        ushort4 zu = *(const ushort4*)(zb4 + ((size_t)(col0 >> 2) << 10) + ((q0 + l31) << 2));
        float4 mv = *(const float4*)(mbl + col0);
        c[4 * cc + 0] = b2f(zu.x) + mv.x;
        c[4 * cc + 1] = b2f(zu.y) + mv.y;
        c[4 * cc + 2] = b2f(zu.z) + mv.z;
        c[4 * cc + 3] = b2f(zu.w) + mv.w;
      }
      // ---- S^T = K @ Q^T + C  (lane: col=q, rows=k)
      c = __builtin_amdgcn_mfma_f32_32x32x16_bf16(kf[kt][0], qf[0], c, 0, 0, 0);
      c = __builtin_amdgcn_mfma_f32_32x32x16_bf16(kf[kt][1], qf[1], c, 0, 0, 0);
      // ---- p = exp2(c); row-sum partials
      float p[16];
#pragma unroll
      for (int j = 0; j < 16; j++) {
        p[j] = __builtin_amdgcn_exp2f(c[j]);
        if (j & 1) ls1 += p[j]; else ls0 += p[j];
      }
      // ---- pack to bf16 words (compiler-managed cvt_pk + permlane)
      unsigned wd[8];
#pragma unroll
      for (int r = 0; r < 8; r++) wd[r] = pkbf16(p[2 * r], p[2 * r + 1]);
      {
        uint2v r0 = __builtin_amdgcn_permlane32_swap(wd[0], wd[2], false, false);
        wd[0] = r0[0]; wd[2] = r0[1];
        uint2v r1 = __builtin_amdgcn_permlane32_swap(wd[1], wd[3], false, false);
        wd[1] = r1[0]; wd[3] = r1[1];
        uint2v r2 = __builtin_amdgcn_permlane32_swap(wd[4], wd[6], false, false);
        wd[4] = r2[0]; wd[6] = r2[1];
        uint2v r3 = __builtin_amdgcn_permlane32_swap(wd[5], wd[7], false, false);
        wd[5] = r3[0]; wd[7] = r3[1];
      }
      union { unsigned u[4]; short8 s8; } pa0, pa1;
      pa0.u[0] = wd[0]; pa0.u[1] = wd[1]; pa0.u[2] = wd[2]; pa0.u[3] = wd[3];
      pa1.u[0] = wd[4]; pa1.u[1] = wd[5]; pa1.u[2] = wd[6]; pa1.u[3] = wd[7];
      // ---- O[q][d] += P @ V
      oacc = __builtin_amdgcn_mfma_f32_32x32x16_bf16(pa0.s8, vf[kt][0], oacc, 0, 0, 0);
      oacc = __builtin_amdgcn_mfma_f32_32x32x16_bf16(pa1.s8, vf[kt][1], oacc, 0, 0, 0);
    }
  }
  // ---- finalize row sums (lane holds q=l31; halves hold disjoint k-sets)
  float lv = ls0 + ls1;
  lv += __shfl_xor(lv, 32, 64);
  float inv = 1.0f / lv;
  // ---- normalize, gate, store (O layout: col=l31=d, row q = (j&3)+8*(j>>2)+4*l5)
#pragma unroll
  for (int j = 0; j < 16; j++) {
    int qrow = (j & 3) + 8 * (j >> 2) + 4 * l5;
    float invj = __shfl(inv, qrow, 64);
    int q = q0 + qrow;
    size_t ob = ((size_t)s * 256 + q) * 256 + h * 32 + l31;
    float gv = b2f(gb[ob]);
    og[ob] = f2bb(oacc[j] * invj * gv);
  }
}

// ---------- kernel 5: 128x128-tile MFMA GEMM  og @ WO + bo -> out f32 ----------
__global__ __launch_bounds__(256) void k_out(const u16* __restrict__ og,
                                             const u16* __restrict__ wot,
                                             const float* __restrict__ bo,
                                             float* __restrict__ out) {
  __shared__ __align__(16) u16 lds[4 * 8192];
  int tid = threadIdx.x;
  int w = tid >> 6, l = tid & 63;
  int l15 = l & 15, lg = l >> 4;
  int wr = w >> 1, wc = w & 1;
  int grow0 = blockIdx.x * 128;
  int ct0 = blockIdx.y * 128;
  const u16* asrc = og + (size_t)grow0 * 256;
  const u16* bsrc = wot + (size_t)ct0 * 256;

  stage_tile(asrc, lds, w, l);
  stage_tile(bsrc, lds + 16384, w, l);
  __syncthreads();

  f32x4 acc[4][4];
#pragma unroll
  for (int mi = 0; mi < 4; mi++)
#pragma unroll
    for (int ni = 0; ni < 4; ni++) acc[mi][ni] = (f32x4){0.f, 0.f, 0.f, 0.f};

#pragma unroll
  for (int kt = 0; kt < 4; kt++) {
    if (kt < 3) {
      stage_tile(asrc + (kt + 1) * 64, lds + ((kt + 1) & 1) * 8192, w, l);
      stage_tile(bsrc + (kt + 1) * 64, lds + 16384 + ((kt + 1) & 1) * 8192, w, l);
    }
    const u16* Ab = lds + (kt & 1) * 8192;
    const u16* Bb = lds + 16384 + (kt & 1) * 8192;
#pragma unroll
    for (int ks = 0; ks < 2; ks++) {
      short8 af[4], bf[4];
#pragma unroll
      for (int i = 0; i < 4; i++) {
        int ra = wr * 64 + i * 16 + l15;
        af[i] = *(const short8*)(Ab + ra * 64 + (((ks * 4 + lg) ^ (ra & 7)) << 3));
        int rb = wc * 64 + i * 16 + l15;
        bf[i] = *(const short8*)(Bb + rb * 64 + (((ks * 4 + lg) ^ (rb & 7)) << 3));
      }
#pragma unroll
      for (int mi = 0; mi < 4; mi++)
#pragma unroll
        for (int ni = 0; ni < 4; ni++)
          acc[mi][ni] =
              __builtin_amdgcn_mfma_f32_16x16x32_bf16(af[mi], bf[ni], acc[mi][ni], 0, 0, 0);
    }
    __syncthreads();
  }

  int cout_base = ct0 + wc * 64;
#pragma unroll
  for (int ni = 0; ni < 4; ni++) {
    int cout = cout_base + ni * 16 + l15;
    float bov = bo[cout];
#pragma unroll
    for (int mi = 0; mi < 4; mi++)
#pragma unroll
      for (int j = 0; j < 4; j++)
        out[(size_t)(grow0 + wr * 64 + mi * 16 + lg * 4 + j) * 256 + cout] =
            acc[mi][ni][j] + bov;
  }
}

extern "C" void kernel_launch(void* const* d_in, const int* in_sizes, int n_in,
                              void* d_out, int out_size, void* d_ws, size_t ws_size,
                              hipStream_t stream) {
  const float* m      = (const float*)d_in[0];
  const float* z      = (const float*)d_in[1];
  const float* mask   = (const float*)d_in[2];
  const float* ln_m_g = (const float*)d_in[3];
  const float* ln_m_b = (const float*)d_in[4];
  const float* ln_z_g = (const float*)d_in[5];
  const float* ln_z_b = (const float*)d_in[6];
  const float* wz     = (const float*)d_in[7];
  const float* wq     = (const float*)d_in[8];
  const float* wk     = (const float*)d_in[9];
  const float* wv     = (const float*)d_in[10];
  const float* wg     = (const float*)d_in[11];
  const float* bg     = (const float*)d_in[12];
  const float* wo     = (const float*)d_in[13];
  const float* bo     = (const float*)d_in[14];
  float* out = (float*)d_out;

  char* ws = (char*)d_ws;
  const size_t MiB = 1u << 20;
  u16* zbb     = (u16*)(ws);                        // 1 MiB  [h][col>>2][q][col&3] bf16
  u16* wcat_t  = (u16*)(ws + 2 * MiB);              // 512 KiB
  u16* wot     = (u16*)(ws + 2 * MiB + 512 * 1024); // 128 KiB
  u16* mln     = (u16*)(ws + 3 * MiB);              // 16 MiB
  u16* qb      = (u16*)(ws + 19 * MiB);             // 16 MiB  [s][h][r][d]
  u16* kb      = (u16*)(ws + 35 * MiB);             // 16 MiB  [s][h][r][d]
  u16* vt      = (u16*)(ws + 51 * MiB);             // 16 MiB  V frag layout
  u16* gb      = (u16*)(ws + 67 * MiB);             // 16 MiB  [row][hd]
  u16* ogb     = (u16*)(ws + 83 * MiB);             // 16 MiB  [row][hd]
  (void)in_sizes; (void)n_in; (void)out_size; (void)ws_size;

  k_pre<<<4176, 256, 0, stream>>>(m, ln_m_g, ln_m_b, z, ln_z_g, ln_z_b, wz,
                                  wq, wk, wv, wg, wo, mln, zbb, wcat_t, wot);
  k_proj<<<dim3(256, 8), 256, 0, stream>>>(mln, wcat_t, bg, qb, kb, vt, gb);
  k_attn<<<S * H * 2, 256, 0, stream>>>(qb, kb, vt, gb, zbb, mask, ogb);
  k_out<<<dim3(256, 2), 256, 0, stream>>>(ogb, wot, bo, out);
}

// Round 14
// 115.602 us; speedup vs baseline: 2.9664x; 1.0297x over previous
//
#include <hip/hip_runtime.h>
#include <hip/hip_bf16.h>
#include <stdint.h>

#define S 128
#define R 256
#define CM 256
#define CZ 128
#define H 8
#define D 32

typedef __attribute__((ext_vector_type(8))) short short8;
typedef __attribute__((ext_vector_type(4))) float f32x4;
typedef __attribute__((ext_vector_type(16))) float f32x16;
typedef __attribute__((ext_vector_type(2))) unsigned uint2v;
typedef unsigned short u16;

#define LOG2E 1.4426950408889634f

// ---------- helpers ----------
__device__ __forceinline__ float wsum(float v) {
#pragma unroll
  for (int o = 32; o > 0; o >>= 1) v += __shfl_xor(v, o, 64);
  return v;
}
__device__ __forceinline__ u16 f2bb(float f) {
  unsigned u = __float_as_uint(f);
  return (u16)((u + 0x7fffu + ((u >> 16) & 1u)) >> 16);
}
__device__ __forceinline__ float b2f(u16 u) {
  return __uint_as_float(((unsigned)u) << 16);
}
__device__ __forceinline__ unsigned pkbf16(float a, float b) {
  __hip_bfloat162 t = __float22bfloat162_rn(make_float2(a, b));
  union { __hip_bfloat162 h; unsigned u; } cv;
  cv.h = t;
  return cv.u;
}
__device__ __forceinline__ void gl_lds16(const u16* g, u16* l) {
  __builtin_amdgcn_global_load_lds(
      (const __attribute__((address_space(1))) unsigned int*)g,
      (__attribute__((address_space(3))) unsigned int*)l, 16, 0, 0);
}

// stage a [128 rows][64 cols] bf16 tile (src row stride 256 elems) into linear LDS.
__device__ __forceinline__ void stage_tile(const u16* __restrict__ src, u16* lbase,
                                           int w, int l) {
#pragma unroll
  for (int it = 0; it < 4; it++) {
    int rbase = it * 32 + w * 8;
    int row = rbase + (l >> 3);
    int gc8 = (l & 7) ^ (row & 7);
    gl_lds16(src + (size_t)row * 256 + gc8 * 8, lbase + rbase * 64);
  }
}

// ---------- kernel 1 (fused pre-stage): prep | zbias | lnm by blockIdx range ----------
// blocks [0, 80):      weights -> bf16 transposed (qscale*log2e folded)
// blocks [80, 2128):   pair bias -> zbb[h][col>>2][q][col&3] (log2e folded)
// blocks [2128, 4176): LN(m) -> bf16 mln (16 rows/block, 16 lanes/row)
__global__ __launch_bounds__(256, 4) void k_pre(const float* __restrict__ m,
                                                const float* __restrict__ ln_m_g,
                                                const float* __restrict__ ln_m_b,
                                                const float* __restrict__ z,
                                                const float* __restrict__ ln_z_g,
                                                const float* __restrict__ ln_z_b,
                                                const float* __restrict__ wz,
                                                const float* __restrict__ wq,
                                                const float* __restrict__ wk,
                                                const float* __restrict__ wv,
                                                const float* __restrict__ wg,
                                                const float* __restrict__ wo,
                                                u16* __restrict__ mln,
                                                u16* __restrict__ zbb,
                                                u16* __restrict__ wcat_t,
                                                u16* __restrict__ wot) {
  __shared__ float t[64][65];
  int bid = blockIdx.x;
  int tid = threadIdx.x;

  if (bid < 80) {
    // ---- weight prep ----
    int mat = bid >> 4;   // 0..4
    int bx = bid & 15;
    const float* src = (mat == 0) ? wq : (mat == 1) ? wk : (mat == 2) ? wv
                       : (mat == 3) ? wg : wo;
    float scale = (mat == 0) ? 0.17677669529663687f * LOG2E : 1.0f;
    u16* dst = (mat < 4) ? (wcat_t + mat * 256 * 256) : wot;
    int ti = bx >> 2, tj = bx & 3;
    int cc = tid & 63, rr4 = tid >> 6;
#pragma unroll
    for (int it = 0; it < 16; it++) {
      int ic = it * 4 + rr4;
      t[ic][cc] = src[(tj * 64 + ic) * 256 + ti * 64 + cc];
    }
    __syncthreads();
#pragma unroll
    for (int it = 0; it < 16; it++) {
      int oh = it * 4 + rr4;
      dst[(ti * 64 + oh) * 256 + tj * 64 + cc] = f2bb(t[cc][oh] * scale);
    }
    return;
  }

  if (bid < 2128) {
    // ---- pair bias -> interleaved bf16, wz register-pipelined, LDS-coalesced store ----
    u16* zsh = (u16*)t;  // [8][32] u16 overlay (512 B)
    int bx = bid - 80;
    int l = tid & 63, w = tid >> 6;
    int psub = l >> 3, cg = l & 7;
    int op = bx * 32 + w * 8 + psub;   // op = q*256 + col (z pair index)
    const float* zr = z + (size_t)op * CZ;
    float4 v[4];
#pragma unroll
    for (int i = 0; i < 4; i++) v[i] = *(const float4*)(zr + i * 32 + cg * 4);
    // preload wz for i=0 (independent of z)
    float4 wa[4], wb[4];
#pragma unroll
    for (int jj = 0; jj < 4; jj++) {
      wa[jj] = *(const float4*)(wz + (cg * 4 + jj) * 8);
      wb[jj] = *(const float4*)(wz + (cg * 4 + jj) * 8 + 4);
    }
    float sum = 0.f, ssq = 0.f;
#pragma unroll
    for (int i = 0; i < 4; i++) {
      sum += v[i].x + v[i].y + v[i].z + v[i].w;
      ssq += v[i].x * v[i].x + v[i].y * v[i].y + v[i].z * v[i].z + v[i].w * v[i].w;
    }
    sum += __shfl_xor(sum, 1, 64); sum += __shfl_xor(sum, 2, 64); sum += __shfl_xor(sum, 4, 64);
    ssq += __shfl_xor(ssq, 1, 64); ssq += __shfl_xor(ssq, 2, 64); ssq += __shfl_xor(ssq, 4, 64);
    float mu = sum * (1.0f / CZ);
    float rs = rsqrtf(ssq * (1.0f / CZ) - mu * mu + 1e-5f);
    float ph[8];
#pragma unroll
    for (int hh = 0; hh < 8; hh++) ph[hh] = 0.f;
#pragma unroll
    for (int i = 0; i < 4; i++) {
      int c0 = i * 32 + cg * 4;
      float4 gg = *(const float4*)(ln_z_g + c0);
      float4 bb = *(const float4*)(ln_z_b + c0);
      float n0 = (v[i].x - mu) * rs * gg.x + bb.x;
      float n1 = (v[i].y - mu) * rs * gg.y + bb.y;
      float n2 = (v[i].z - mu) * rs * gg.z + bb.z;
      float n3 = (v[i].w - mu) * rs * gg.w + bb.w;
      // preload next i's wz while this i's FMAs run
      float4 na[4], nb[4];
      if (i < 3) {
#pragma unroll
        for (int jj = 0; jj < 4; jj++) {
          na[jj] = *(const float4*)(wz + ((i + 1) * 32 + cg * 4 + jj) * 8);
          nb[jj] = *(const float4*)(wz + ((i + 1) * 32 + cg * 4 + jj) * 8 + 4);
        }
      }
#pragma unroll
      for (int jj = 0; jj < 4; jj++) {
        float nj = (jj == 0) ? n0 : (jj == 1) ? n1 : (jj == 2) ? n2 : n3;
        ph[0] = fmaf(nj, wa[jj].x, ph[0]); ph[1] = fmaf(nj, wa[jj].y, ph[1]);
        ph[2] = fmaf(nj, wa[jj].z, ph[2]); ph[3] = fmaf(nj, wa[jj].w, ph[3]);
        ph[4] = fmaf(nj, wb[jj].x, ph[4]); ph[5] = fmaf(nj, wb[jj].y, ph[5]);
        ph[6] = fmaf(nj, wb[jj].z, ph[6]); ph[7] = fmaf(nj, wb[jj].w, ph[7]);
      }
      if (i < 3) {
#pragma unroll
        for (int jj = 0; jj < 4; jj++) { wa[jj] = na[jj]; wb[jj] = nb[jj]; }
      }
    }
    // component-splitting reduce over the 8 lanes of the pair (xor 1,2,4)
    float a[4];
#pragma unroll
    for (int j = 0; j < 4; j++) {
      float keep = (l & 1) ? ph[4 + j] : ph[j];
      float send = (l & 1) ? ph[j] : ph[4 + j];
      a[j] = keep + __shfl_xor(send, 1, 64);
    }
    float b2[2];
#pragma unroll
    for (int j = 0; j < 2; j++) {
      float keep = (l & 2) ? a[2 + j] : a[j];
      float send = (l & 2) ? a[j] : a[2 + j];
      b2[j] = keep + __shfl_xor(send, 2, 64);
    }
    float keep = (l & 4) ? b2[1] : b2[0];
    float send = (l & 4) ? b2[0] : b2[1];
    float c = keep + __shfl_xor(send, 4, 64);
    int hh = 4 * (l & 1) + (l & 2) + ((l & 4) >> 2);
    // stage into LDS tile [h][colloc], then wave 0 writes coalesced 8B chunks
    zsh[hh * 32 + w * 8 + psub] = f2bb(c * LOG2E);
    __syncthreads();
    if (tid < 64) {
      int h = tid >> 3, c8 = tid & 7;
      ushort4 v4;
      v4.x = zsh[h * 32 + c8 * 4 + 0];
      v4.y = zsh[h * 32 + c8 * 4 + 1];
      v4.z = zsh[h * 32 + c8 * 4 + 2];
      v4.w = zsh[h * 32 + c8 * 4 + 3];
      int op0 = bx * 32;
      int q = op0 >> 8;
      int cb4 = ((op0 & 255) >> 2) + c8;
      *(ushort4*)(zbb + (size_t)h * 65536 + (size_t)cb4 * 1024 + (size_t)q * 4) = v4;
    }
    return;
  }

  // ---- LN(m) -> bf16: 16 rows/block, 16 lanes/row, 64B/lane ----
  {
    int bid3 = bid - 2128;
    int grp = tid >> 4, l15 = tid & 15;
    size_t row = (size_t)bid3 * 16 + grp;
    const float* mr = m + row * 256 + l15 * 4;
    float4 v[4];
#pragma unroll
    for (int i = 0; i < 4; i++) v[i] = *(const float4*)(mr + i * 64);
    float sum = 0.f, ssq = 0.f;
#pragma unroll
    for (int i = 0; i < 4; i++) {
      sum += v[i].x + v[i].y + v[i].z + v[i].w;
      ssq += v[i].x * v[i].x + v[i].y * v[i].y + v[i].z * v[i].z + v[i].w * v[i].w;
    }
    sum += __shfl_xor(sum, 1, 64); sum += __shfl_xor(sum, 2, 64);
    sum += __shfl_xor(sum, 4, 64); sum += __shfl_xor(sum, 8, 64);
    ssq += __shfl_xor(ssq, 1, 64); ssq += __shfl_xor(ssq, 2, 64);
    ssq += __shfl_xor(ssq, 4, 64); ssq += __shfl_xor(ssq, 8, 64);
    float mu = sum * (1.f / 256);
    float rs = rsqrtf(ssq * (1.f / 256) - mu * mu + 1e-5f);
#pragma unroll
    for (int i = 0; i < 4; i++) {
      const float4 gg = *(const float4*)(ln_m_g + l15 * 4 + i * 64);
      const float4 bb = *(const float4*)(ln_m_b + l15 * 4 + i * 64);
      ushort4 o;
      o.x = f2bb((v[i].x - mu) * rs * gg.x + bb.x);
      o.y = f2bb((v[i].y - mu) * rs * gg.y + bb.y);
      o.z = f2bb((v[i].z - mu) * rs * gg.z + bb.z);
      o.w = f2bb((v[i].w - mu) * rs * gg.w + bb.w);
      *(ushort4*)(mln + row * 256 + i * 64 + l15 * 4) = o;
    }
  }
}

// ---------- kernel 3: 128x128-tile MFMA GEMM  mln @ Wcat -> q/k/vfrag/g ----------
__global__ __launch_bounds__(256) void k_proj(const u16* __restrict__ mln,
                                              const u16* __restrict__ wcat_t,
                                              const float* __restrict__ bg,
                                              u16* __restrict__ qb,
                                              u16* __restrict__ kbuf,
                                              u16* __restrict__ vt,
                                              u16* __restrict__ gb) {
  __shared__ __align__(16) u16 lds[4 * 8192];  // A0 A1 B0 B1 (16KB each)
  int tid = threadIdx.x;
  int w = tid >> 6, l = tid & 63;
  int l15 = l & 15, lg = l >> 4;
  int wr = w >> 1, wc = w & 1;
  int grow0 = blockIdx.x * 128;
  int hdt0 = blockIdx.y * 128;
  const u16* asrc = mln + (size_t)grow0 * 256;
  const u16* bsrc = wcat_t + (size_t)hdt0 * 256;

  stage_tile(asrc, lds, w, l);
  stage_tile(bsrc, lds + 16384, w, l);
  __syncthreads();

  f32x4 acc[4][4];
#pragma unroll
  for (int mi = 0; mi < 4; mi++)
#pragma unroll
    for (int ni = 0; ni < 4; ni++) acc[mi][ni] = (f32x4){0.f, 0.f, 0.f, 0.f};

#pragma unroll
  for (int kt = 0; kt < 4; kt++) {
    if (kt < 3) {
      stage_tile(asrc + (kt + 1) * 64, lds + ((kt + 1) & 1) * 8192, w, l);
      stage_tile(bsrc + (kt + 1) * 64, lds + 16384 + ((kt + 1) & 1) * 8192, w, l);
    }
    const u16* Ab = lds + (kt & 1) * 8192;
    const u16* Bb = lds + 16384 + (kt & 1) * 8192;
#pragma unroll
    for (int ks = 0; ks < 2; ks++) {
      short8 af[4], bf[4];
#pragma unroll
      for (int i = 0; i < 4; i++) {
        int ra = wr * 64 + i * 16 + l15;
        af[i] = *(const short8*)(Ab + ra * 64 + (((ks * 4 + lg) ^ (ra & 7)) << 3));
        int rb = wc * 64 + i * 16 + l15;
        bf[i] = *(const short8*)(Bb + rb * 64 + (((ks * 4 + lg) ^ (rb & 7)) << 3));
      }
#pragma unroll
      for (int mi = 0; mi < 4; mi++)
#pragma unroll
        for (int ni = 0; ni < 4; ni++)
          acc[mi][ni] =
              __builtin_amdgcn_mfma_f32_16x16x32_bf16(af[mi], bf[ni], acc[mi][ni], 0, 0, 0);
    }
    __syncthreads();
  }

  // ---- epilogue: re-stage through LDS for coalesced uint4 stores ----
  int by = blockIdx.y;
  int mat = by >> 1;            // 0:q 1:k 2:v(frag layout) 3:g
  int s = grow0 >> 8, r0 = grow0 & 255;
  int hbase = (by & 1) * 128;
  u16* stg = lds;               // [128][136] bf16

  if (mat == 2) {
    // stage transposed: stg[hd_loc][k_loc]
#pragma unroll
    for (int mi = 0; mi < 4; mi++)
#pragma unroll
      for (int ni = 0; ni < 4; ni++)
#pragma unroll
        for (int j = 0; j < 4; j++) {
          int rl = wr * 64 + mi * 16 + lg * 4 + j;
          int hl = wc * 64 + ni * 16 + l15;
          stg[hl * 136 + rl] = f2bb(acc[mi][ni][j]);
        }
    __syncthreads();
    // frag layout: vt[((s*8+h)*16 + k16)*512 + l5*256 + d*8 + (k&7)]
#pragma unroll
    for (int it = 0; it < 8; it++) {
      int idx = it * 256 + tid;
      int hd_l = idx & 127, k8 = idx >> 7;      // k8: 0..15 (8-element k chunk)
      uint4 val = *(const uint4*)(stg + hd_l * 136 + k8 * 8);
      int hd = hbase + hd_l;
      int h = hd >> 5, d = hd & 31;
      int kg = r0 + k8 * 8;
      size_t off = (((size_t)(s * 8 + h) * 16 + (kg >> 4)) * 2 + ((kg >> 3) & 1)) * 256 + d * 8;
      *(uint4*)(vt + off) = val;
    }
  } else {
    float bgv[4];
    if (mat == 3) {
#pragma unroll
      for (int ni = 0; ni < 4; ni++) bgv[ni] = bg[hbase + wc * 64 + ni * 16 + l15];
    }
#pragma unroll
    for (int mi = 0; mi < 4; mi++)
#pragma unroll
      for (int ni = 0; ni < 4; ni++)
#pragma unroll
        for (int j = 0; j < 4; j++) {
          int rl = wr * 64 + mi * 16 + lg * 4 + j;
          int hl = wc * 64 + ni * 16 + l15;
          float v = acc[mi][ni][j];
          if (mat == 3) v = 1.0f / (1.0f + __expf(-(v + bgv[ni])));
          stg[rl * 136 + hl] = f2bb(v);
        }
    __syncthreads();
#pragma unroll
    for (int it = 0; it < 8; it++) {
      int idx = it * 256 + tid;
      int rl = idx >> 4, c = idx & 15;
      uint4 val = *(const uint4*)(stg + rl * 136 + c * 8);
      int hd = hbase + c * 8;
      if (mat == 3) {
        *(uint4*)(gb + (size_t)(grow0 + rl) * 256 + hd) = val;
      } else {
        u16* dst = (mat == 0) ? qb : kbuf;
        *(uint4*)(dst + ((size_t)(s * 8 + (hd >> 5)) * 256 + r0 + rl) * 32 + (hd & 31)) = val;
      }
    }
  }
}

// ---------- kernel 4: swapped-QK 32x32 MFMA flash attention, register softmax ----------
// Grid: S*H*2 blocks; each wave owns ONE 32-q-row tile (low register pressure, no spill).
__global__ __launch_bounds__(256) void k_attn(const u16* __restrict__ qb,
                                              const u16* __restrict__ kbuf,
                                              const u16* __restrict__ vt,
                                              const u16* __restrict__ gb,
                                              const u16* __restrict__ zbb,
                                              const float* __restrict__ mask,
                                              u16* __restrict__ og) {
  __shared__ float mbl[256];            // mask bias, log2e folded
  int blk = blockIdx.x;                 // s*16 + h*2 + half
  int s = blk >> 4, h = (blk >> 1) & 7, half = blk & 1;
  int tid = threadIdx.x, w = tid >> 6, l = tid & 63;
  int l31 = l & 31, l5 = l >> 5;
  int q0 = half * 128 + w * 32;
  size_t base = (size_t)(s * 8 + h) * 256 * 32;
  const u16* zb4 = zbb + (size_t)h * 65536;   // [col>>2][q][col&3] bf16, log2e folded

  mbl[tid] = (LOG2E * 1e9f) * (mask[s * 256 + tid] - 1.0f);

  // Q B-frags: Q[q0+l31][dh*16 + l5*8 ..+7]
  short8 qf[2];
#pragma unroll
  for (int dh = 0; dh < 2; dh++)
    qf[dh] = *(const short8*)(qb + base + (size_t)(q0 + l31) * 32 + dh * 16 + l5 * 8);

  f32x16 oacc;
#pragma unroll
  for (int j = 0; j < 16; j++) oacc[j] = 0.f;
  float ls0 = 0.f, ls1 = 0.f;
  __syncthreads();

#pragma unroll
  for (int kb = 0; kb < 4; kb++) {
    int kbase = kb * 64;
    // K A-frags: K[kbase+kt*32+l31][dh*16 + l5*8..]
    short8 kf[2][2];
#pragma unroll
    for (int kt = 0; kt < 2; kt++)
#pragma unroll
      for (int dh = 0; dh < 2; dh++)
        kf[kt][dh] = *(const short8*)(kbuf + base + (size_t)(kbase + kt * 32 + l31) * 32 +
                                      dh * 16 + l5 * 8);
    // V B-frags from frag layout: fully coalesced (16B/lane)
    short8 vf[2][2];
#pragma unroll
    for (int kt = 0; kt < 2; kt++)
#pragma unroll
      for (int ks = 0; ks < 2; ks++)
        vf[kt][ks] = *(const short8*)(vt + ((size_t)(s * 8 + h) * 16 +
                                            (kb * 4 + kt * 2 + ks)) * 512 +
                                      l5 * 256 + l31 * 8);

#pragma unroll
    for (int kt = 0; kt < 2; kt++) {
      // ---- C-init: vectorized z (ushort4 = 4 cols) + LDS mask bias
      f32x16 c;
#pragma unroll
      for (int cc = 0; cc < 4; cc++) {
        int col0 = kbase + kt * 32 + cc * 8 + l5 * 4;
        ushort4 zu = *(const ushort4*)(zb4 + ((size_t)(col0 >> 2) << 10) + ((q0 + l31) << 2));
        float4 mv = *(const float4*)(mbl + col0);
        c[4 * cc + 0] = b2f(zu.x) + mv.x;
        c[4 * cc + 1] = b2f(zu.y) + mv.y;
        c[4 * cc + 2] = b2f(zu.z) + mv.z;
        c[4 * cc + 3] = b2f(zu.w) + mv.w;
      }
      // ---- S^T = K @ Q^T + C  (lane: col=q, rows=k)
      c = __builtin_amdgcn_mfma_f32_32x32x16_bf16(kf[kt][0], qf[0], c, 0, 0, 0);
      c = __builtin_amdgcn_mfma_f32_32x32x16_bf16(kf[kt][1], qf[1], c, 0, 0, 0);
      // ---- p = exp2(c); row-sum partials
      float p[16];
#pragma unroll
      for (int j = 0; j < 16; j++) {
        p[j] = __builtin_amdgcn_exp2f(c[j]);
        if (j & 1) ls1 += p[j]; else ls0 += p[j];
      }
      // ---- pack to bf16 words (compiler-managed cvt_pk + permlane)
      unsigned wd[8];
#pragma unroll
      for (int r = 0; r < 8; r++) wd[r] = pkbf16(p[2 * r], p[2 * r + 1]);
      {
        uint2v r0 = __builtin_amdgcn_permlane32_swap(wd[0], wd[2], false, false);
        wd[0] = r0[0]; wd[2] = r0[1];
        uint2v r1 = __builtin_amdgcn_permlane32_swap(wd[1], wd[3], false, false);
        wd[1] = r1[0]; wd[3] = r1[1];
        uint2v r2 = __builtin_amdgcn_permlane32_swap(wd[4], wd[6], false, false);
        wd[4] = r2[0]; wd[6] = r2[1];
        uint2v r3 = __builtin_amdgcn_permlane32_swap(wd[5], wd[7], false, false);
        wd[5] = r3[0]; wd[7] = r3[1];
      }
      union { unsigned u[4]; short8 s8; } pa0, pa1;
      pa0.u[0] = wd[0]; pa0.u[1] = wd[1]; pa0.u[2] = wd[2]; pa0.u[3] = wd[3];
      pa1.u[0] = wd[4]; pa1.u[1] = wd[5]; pa1.u[2] = wd[6]; pa1.u[3] = wd[7];
      // ---- O[q][d] += P @ V
      oacc = __builtin_amdgcn_mfma_f32_32x32x16_bf16(pa0.s8, vf[kt][0], oacc, 0, 0, 0);
      oacc = __builtin_amdgcn_mfma_f32_32x32x16_bf16(pa1.s8, vf[kt][1], oacc, 0, 0, 0);
    }
  }
  // ---- finalize row sums (lane holds q=l31; halves hold disjoint k-sets)
  float lv = ls0 + ls1;
  lv += __shfl_xor(lv, 32, 64);
  float inv = 1.0f / lv;
  // ---- normalize, gate, store (O layout: col=l31=d, row q = (j&3)+8*(j>>2)+4*l5)
#pragma unroll
  for (int j = 0; j < 16; j++) {
    int qrow = (j & 3) + 8 * (j >> 2) + 4 * l5;
    float invj = __shfl(inv, qrow, 64);
    int q = q0 + qrow;
    size_t ob = ((size_t)s * 256 + q) * 256 + h * 32 + l31;
    float gv = b2f(gb[ob]);
    og[ob] = f2bb(oacc[j] * invj * gv);
  }
}

// ---------- kernel 5: 128x128-tile MFMA GEMM  og @ WO + bo -> out f32 ----------
__global__ __launch_bounds__(256) void k_out(const u16* __restrict__ og,
                                             const u16* __restrict__ wot,
                                             const float* __restrict__ bo,
                                             float* __restrict__ out) {
  __shared__ __align__(16) u16 lds[4 * 8192];
  int tid = threadIdx.x;
  int w = tid >> 6, l = tid & 63;
  int l15 = l & 15, lg = l >> 4;
  int wr = w >> 1, wc = w & 1;
  int grow0 = blockIdx.x * 128;
  int ct0 = blockIdx.y * 128;
  const u16* asrc = og + (size_t)grow0 * 256;
  const u16* bsrc = wot + (size_t)ct0 * 256;

  stage_tile(asrc, lds, w, l);
  stage_tile(bsrc, lds + 16384, w, l);
  __syncthreads();

  f32x4 acc[4][4];
#pragma unroll
  for (int mi = 0; mi < 4; mi++)
#pragma unroll
    for (int ni = 0; ni < 4; ni++) acc[mi][ni] = (f32x4){0.f, 0.f, 0.f, 0.f};

#pragma unroll
  for (int kt = 0; kt < 4; kt++) {
    if (kt < 3) {
      stage_tile(asrc + (kt + 1) * 64, lds + ((kt + 1) & 1) * 8192, w, l);
      stage_tile(bsrc + (kt + 1) * 64, lds + 16384 + ((kt + 1) & 1) * 8192, w, l);
    }
    const u16* Ab = lds + (kt & 1) * 8192;
    const u16* Bb = lds + 16384 + (kt & 1) * 8192;
#pragma unroll
    for (int ks = 0; ks < 2; ks++) {
      short8 af[4], bf[4];
#pragma unroll
      for (int i = 0; i < 4; i++) {
        int ra = wr * 64 + i * 16 + l15;
        af[i] = *(const short8*)(Ab + ra * 64 + (((ks * 4 + lg) ^ (ra & 7)) << 3));
        int rb = wc * 64 + i * 16 + l15;
        bf[i] = *(const short8*)(Bb + rb * 64 + (((ks * 4 + lg) ^ (rb & 7)) << 3));
      }
#pragma unroll
      for (int mi = 0; mi < 4; mi++)
#pragma unroll
        for (int ni = 0; ni < 4; ni++)
          acc[mi][ni] =
              __builtin_amdgcn_mfma_f32_16x16x32_bf16(af[mi], bf[ni], acc[mi][ni], 0, 0, 0);
    }
    __syncthreads();
  }

  int cout_base = ct0 + wc * 64;
#pragma unroll
  for (int ni = 0; ni < 4; ni++) {
    int cout = cout_base + ni * 16 + l15;
    float bov = bo[cout];
#pragma unroll
    for (int mi = 0; mi < 4; mi++)
#pragma unroll
      for (int j = 0; j < 4; j++)
        out[(size_t)(grow0 + wr * 64 + mi * 16 + lg * 4 + j) * 256 + cout] =
            acc[mi][ni][j] + bov;
  }
}

extern "C" void kernel_launch(void* const* d_in, const int* in_sizes, int n_in,
                              void* d_out, int out_size, void* d_ws, size_t ws_size,
                              hipStream_t stream) {
  const float* m      = (const float*)d_in[0];
  const float* z      = (const float*)d_in[1];
  const float* mask   = (const float*)d_in[2];
  const float* ln_m_g = (const float*)d_in[3];
  const float* ln_m_b = (const float*)d_in[4];
  const float* ln_z_g = (const float*)d_in[5];
  const float* ln_z_b = (const float*)d_in[6];
  const float* wz     = (const float*)d_in[7];
  const float* wq     = (const float*)d_in[8];
  const float* wk     = (const float*)d_in[9];
  const float* wv     = (const float*)d_in[10];
  const float* wg     = (const float*)d_in[11];
  const float* bg     = (const float*)d_in[12];
  const float* wo     = (const float*)d_in[13];
  const float* bo     = (const float*)d_in[14];
  float* out = (float*)d_out;

  char* ws = (char*)d_ws;
  const size_t MiB = 1u << 20;
  u16* zbb     = (u16*)(ws);                        // 1 MiB  [h][col>>2][q][col&3] bf16
  u16* wcat_t  = (u16*)(ws + 2 * MiB);              // 512 KiB
  u16* wot     = (u16*)(ws + 2 * MiB + 512 * 1024); // 128 KiB
  u16* mln     = (u16*)(ws + 3 * MiB);              // 16 MiB
  u16* qb      = (u16*)(ws + 19 * MiB);             // 16 MiB  [s][h][r][d]
  u16* kb      = (u16*)(ws + 35 * MiB);             // 16 MiB  [s][h][r][d]
  u16* vt      = (u16*)(ws + 51 * MiB);             // 16 MiB  V frag layout
  u16* gb      = (u16*)(ws + 67 * MiB);             // 16 MiB  [row][hd]
  u16* ogb     = (u16*)(ws + 83 * MiB);             // 16 MiB  [row][hd]
  (void)in_sizes; (void)n_in; (void)out_size; (void)ws_size;

  k_pre<<<4176, 256, 0, stream>>>(m, ln_m_g, ln_m_b, z, ln_z_g, ln_z_b, wz,
                                  wq, wk, wv, wg, wo, mln, zbb, wcat_t, wot);
  k_proj<<<dim3(256, 8), 256, 0, stream>>>(mln, wcat_t, bg, qb, kb, vt, gb);
  k_attn<<<S * H * 2, 256, 0, stream>>>(qb, kb, vt, gb, zbb, mask, ogb);
  k_out<<<dim3(256, 2), 256, 0, stream>>>(ogb, wot, bo, out);
}